// Round 17
// baseline (809.258 us; speedup 1.0000x reference)
//
#include <hip/hip_runtime.h>
#include <cstdint>
#include <cstddef>

using bf16 = __bf16;
typedef __bf16 bf16x8 __attribute__((ext_vector_type(8)));
typedef float f32x4 __attribute__((ext_vector_type(4)));
typedef float f32x16 __attribute__((ext_vector_type(16)));
typedef unsigned int uint4v __attribute__((ext_vector_type(4)));

#define NB 8       // batch
#define DIM 512
#define SEQ 1024
#define NH 8
#define DH 64
#define CONV_INNER 1024
#define KW 31
#define PADW 15
#define HPRA 1056

__device__ __forceinline__ float fsigmoid(float x) { return 1.f / (1.f + __expf(-x)); }
__device__ __forceinline__ float fsilu(float x) { return x * fsigmoid(x); }

__device__ __forceinline__ void gld16(const bf16* g, bf16* l) {
  __builtin_amdgcn_global_load_lds(
      (const __attribute__((address_space(1))) unsigned int*)g,
      (__attribute__((address_space(3))) unsigned int*)l, 16, 0, 0);
}

// ---------------------------------------------------------------- ws guard

__global__ __launch_bounds__(256) void k_diag(float* __restrict__ out, int n, float v) {
  int i = blockIdx.x * 256 + threadIdx.x;
  if (i < n) out[i] = v;
}

// ---------------------------------------------------------------- prep kernels

struct CvtArgs {
  const float* s[10];
  bf16* d[10];
  int cum[11];
};

__global__ __launch_bounds__(256) void k_convert_all(CvtArgs a) {
  int blk = blockIdx.x;
  int seg = 0;
#pragma unroll
  for (int t = 0; t < 10; ++t)
    if (blk >= a.cum[t + 1]) seg = t + 1;
  const float* src = a.s[seg];
  bf16* dst = a.d[seg];
  int i = ((blk - a.cum[seg]) * 256 + threadIdx.x) * 4;
  float4 v = *reinterpret_cast<const float4*>(src + i);
  dst[i]     = (bf16)v.x;
  dst[i + 1] = (bf16)v.y;
  dst[i + 2] = (bf16)v.z;
  dst[i + 3] = (bf16)v.w;
}

// dconv_w [O=1024][I=1024][K=31] fp32 -> wt [k][o][i] bf16 (vectorized 16B stores)
__global__ __launch_bounds__(256) void k_conv_wt(const float* __restrict__ w,
                                                 bf16* __restrict__ wt) {
  __shared__ float t[256 * KW];   // [i_local][k]
  int o = blockIdx.x, i0 = blockIdx.y * 256;
  const float* src = w + (size_t)o * (CONV_INNER * KW) + (size_t)i0 * KW;
  for (int idx = threadIdx.x; idx < 256 * KW; idx += 256) t[idx] = src[idx];
  __syncthreads();
  for (int idx = threadIdx.x; idx < KW * 32; idx += 256) {
    int k = idx >> 5, c = idx & 31;
    bf16x8 v;
#pragma unroll
    for (int e = 0; e < 8; ++e) v[e] = (bf16)t[(c * 8 + e) * KW + k];
    *reinterpret_cast<bf16x8*>(
        &wt[((size_t)k * CONV_INNER + o) * CONV_INNER + i0 + c * 8]) = v;
  }
}

__global__ __launch_bounds__(256) void k_pad_zero(bf16* __restrict__ hpad) {
  int i = blockIdx.x * 256 + threadIdx.x;
  int b = i / (32 * 128);
  int r = (i >> 7) & 31;
  int c8 = (i & 127) * 8;
  int row = (r < PADW) ? r : 1024 + r;
  uint4v z = {0u, 0u, 0u, 0u};
  *reinterpret_cast<uint4v*>(&hpad[((size_t)b * HPRA + row) * CONV_INNER + c8]) = z;
}

__global__ __launch_bounds__(256) void k_transpose_in(const float* __restrict__ x,
                                                      const float* __restrict__ g,
                                                      const float* __restrict__ bvec,
                                                      float* __restrict__ xT,
                                                      bf16* __restrict__ xbn) {
  __shared__ float t[32][33];
  int s0 = blockIdx.x * 32, c0 = blockIdx.y * 32, b = blockIdx.z;
  int col = threadIdx.x & 31, rq = threadIdx.x >> 5;
#pragma unroll
  for (int i = 0; i < 4; ++i) {
    int row = rq + i * 8;
    t[row][col] = x[((size_t)b * DIM + c0 + row) * SEQ + s0 + col];
  }
  __syncthreads();
  float gg = g[c0 + col], bb = bvec[c0 + col];
#pragma unroll
  for (int i = 0; i < 4; ++i) {
    int srow = rq + i * 8;
    float v = t[col][srow];
    size_t off = ((size_t)b * SEQ + s0 + srow) * DIM + c0 + col;
    xT[off] = v;
    xbn[off] = (bf16)(v * gg + bb);
  }
}

__global__ __launch_bounds__(256) void k_concat_bias(const float* __restrict__ bq,
                                                     const float* __restrict__ bk,
                                                     const float* __restrict__ bv,
                                                     float* __restrict__ qb) {
  int i = blockIdx.x * 256 + threadIdx.x;
  if (i < 512) qb[i] = bq[i];
  else if (i < 1024) qb[i] = bk[i - 512];
  else if (i < 1536) qb[i] = bv[i - 1024];
}

// ---------------------------------------------------------------- generic GEMM v2
// Epilogues: 0 silu->bf16 | 1 res+0.5a, BN | 2 bf16 | 3 res+a, BN | 5 final BN
// transposed | 6 qkv: Q,K -> outb; V -> vtout transposed [bh][d][s]
template <int EPI>
__global__ __launch_bounds__(256) void k_gemm(const bf16* __restrict__ A,
                                              const bf16* __restrict__ W,
                                              const float* __restrict__ bias,
                                              const float* __restrict__ res,
                                              const float* __restrict__ g,
                                              const float* __restrict__ bb,
                                              float* __restrict__ outf,
                                              bf16* __restrict__ outb,
                                              bf16* __restrict__ vtout, int N, int K) {
  __shared__ __align__(16) bf16 sA[2][128 * 64];
  __shared__ __align__(16) bf16 sB[2][128 * 64];
  const int tid = threadIdx.x;
  const int b = blockIdx.z;
  const int m0 = blockIdx.y * 128, n0 = blockIdx.x * 128;
  const int lane = tid & 63, wid = tid >> 6;
  const int wm = (wid & 1) * 64, wn = (wid >> 1) * 64;
  const int fr = lane & 15, fg = lane >> 4;
  const int srow = lane >> 3;
  const int scol = ((lane & 7) ^ srow) * 8;

  f32x4 acc[4][4];
#pragma unroll
  for (int i = 0; i < 4; ++i)
#pragma unroll
    for (int j = 0; j < 4; ++j) acc[i][j] = (f32x4)0.f;

  const bf16* Abase = A + ((size_t)b * SEQ + m0 + srow) * K + scol;
  const bf16* Wbase = W + (size_t)(n0 + srow) * K + scol;
  const int nch = K >> 6;

#pragma unroll
  for (int c = 0; c < 4; ++c) {
    const int ch = wid + c * 4;
    gld16(Abase + (size_t)(ch * 8) * K, &sA[0][ch * 512]);
    gld16(Wbase + (size_t)(ch * 8) * K, &sB[0][ch * 512]);
  }
  __syncthreads();

  int buf = 0;
  for (int kt = 0; kt < nch; ++kt) {
    if (kt + 1 < nch) {
      const int kc = (kt + 1) * 64;
#pragma unroll
      for (int c = 0; c < 4; ++c) {
        const int ch = wid + c * 4;
        gld16(Abase + (size_t)(ch * 8) * K + kc, &sA[buf ^ 1][ch * 512]);
        gld16(Wbase + (size_t)(ch * 8) * K + kc, &sB[buf ^ 1][ch * 512]);
      }
    }
#pragma unroll
    for (int kk = 0; kk < 2; ++kk) {
      const int cg = kk * 4 + fg;
      bf16x8 aF[4], bF[4];
#pragma unroll
      for (int i = 0; i < 4; ++i) {
        const int ar = wm + i * 16 + fr;
        aF[i] = *reinterpret_cast<const bf16x8*>(
            &sA[buf][ar * 64 + ((cg ^ (ar & 7)) * 8)]);
        const int br = wn + i * 16 + fr;
        bF[i] = *reinterpret_cast<const bf16x8*>(
            &sB[buf][br * 64 + ((cg ^ (br & 7)) * 8)]);
      }
#pragma unroll
      for (int mi = 0; mi < 4; ++mi)
#pragma unroll
        for (int ni = 0; ni < 4; ++ni)
          acc[mi][ni] = __builtin_amdgcn_mfma_f32_16x16x32_bf16(aF[mi], bF[ni],
                                                                acc[mi][ni], 0, 0, 0);
    }
    __syncthreads();
    buf ^= 1;
  }

#pragma unroll
  for (int mi = 0; mi < 4; ++mi) {
#pragma unroll
    for (int ni = 0; ni < 4; ++ni) {
      int ncol = n0 + wn + ni * 16 + fr;
      float bv = bias[ncol];
      if constexpr (EPI == 5) {
        float gg = g[ncol], bbv = bb[ncol];
        int mrow0 = m0 + wm + mi * 16 + fg * 4;
        float v[4];
#pragma unroll
        for (int j = 0; j < 4; ++j) {
          float a = acc[mi][ni][j] + bv;
          float r = res[((size_t)b * SEQ + mrow0 + j) * 512 + ncol] + 0.5f * a;
          v[j] = r * gg + bbv;
        }
        *reinterpret_cast<float4*>(outf + ((size_t)b * 512 + ncol) * SEQ + mrow0) =
            make_float4(v[0], v[1], v[2], v[3]);
      } else {
#pragma unroll
        for (int j = 0; j < 4; ++j) {
          int mrow = m0 + wm + mi * 16 + fg * 4 + j;
          size_t off = ((size_t)b * SEQ + mrow) * N + ncol;
          float a = acc[mi][ni][j] + bv;
          if constexpr (EPI == 0) {
            outb[off] = (bf16)fsilu(a);
          } else if constexpr (EPI == 2) {
            outb[off] = (bf16)a;
          } else if constexpr (EPI == 6) {
            if (ncol < 1024) {
              outb[off] = (bf16)a;
            } else {
              int d = ncol - 1024;
              vtout[(((size_t)b * 8 + (d >> 6)) * 64 + (d & 63)) * SEQ + mrow] =
                  (bf16)a;
            }
          } else if constexpr (EPI == 1) {
            float r = res[off] + 0.5f * a;
            outf[off] = r;
            outb[off] = (bf16)(r * g[ncol] + bb[ncol]);
          } else if constexpr (EPI == 3) {
            float r = res[off] + a;
            outf[off] = r;
            outb[off] = (bf16)(r * g[ncol] + bb[ncol]);
          }
        }
      }
    }
  }
}

// ---------------------------------------------------------------- pw1 + GLU fused v2
__global__ __launch_bounds__(256) void k_pw1_glu(const bf16* __restrict__ A,
                                                 const bf16* __restrict__ W,
                                                 const float* __restrict__ bias,
                                                 bf16* __restrict__ hpad) {
  __shared__ __align__(16) bf16 sA[128 * 64];
  __shared__ __align__(16) bf16 sBa[128 * 64];
  __shared__ __align__(16) bf16 sBg[128 * 64];
  const int tid = threadIdx.x;
  const int b = blockIdx.z;
  const int m0 = blockIdx.y * 128, n0 = blockIdx.x * 128;
  const int lane = tid & 63, wid = tid >> 6;
  const int wm = (wid & 1) * 64, wn = (wid >> 1) * 64;
  const int fr = lane & 15, fg = lane >> 4;
  const int srow = lane >> 3;
  const int scol = ((lane & 7) ^ srow) * 8;
  const int K = 512;

  f32x4 accA[4][4], accG[4][4];
#pragma unroll
  for (int i = 0; i < 4; ++i)
#pragma unroll
    for (int j = 0; j < 4; ++j) { accA[i][j] = (f32x4)0.f; accG[i][j] = (f32x4)0.f; }

  const bf16* Abase = A + ((size_t)b * SEQ + m0 + srow) * K + scol;
  const bf16* WaB = W + (size_t)(n0 + srow) * K + scol;
  const bf16* WgB = W + (size_t)(n0 + 1024 + srow) * K + scol;

  for (int kt = 0; kt < 8; ++kt) {
    const int kc = kt * 64;
#pragma unroll
    for (int c = 0; c < 4; ++c) {
      const int ch = wid + c * 4;
      gld16(Abase + (size_t)(ch * 8) * K + kc, &sA[ch * 512]);
      gld16(WaB + (size_t)(ch * 8) * K + kc, &sBa[ch * 512]);
      gld16(WgB + (size_t)(ch * 8) * K + kc, &sBg[ch * 512]);
    }
    __syncthreads();
#pragma unroll
    for (int kk = 0; kk < 2; ++kk) {
      const int cg = kk * 4 + fg;
      bf16x8 aF[4], bFa[4], bFg[4];
#pragma unroll
      for (int i = 0; i < 4; ++i) {
        const int ar = wm + i * 16 + fr;
        aF[i] = *reinterpret_cast<const bf16x8*>(
            &sA[ar * 64 + ((cg ^ (ar & 7)) * 8)]);
        const int br = wn + i * 16 + fr;
        bFa[i] = *reinterpret_cast<const bf16x8*>(
            &sBa[br * 64 + ((cg ^ (br & 7)) * 8)]);
        bFg[i] = *reinterpret_cast<const bf16x8*>(
            &sBg[br * 64 + ((cg ^ (br & 7)) * 8)]);
      }
#pragma unroll
      for (int mi = 0; mi < 4; ++mi)
#pragma unroll
        for (int ni = 0; ni < 4; ++ni) {
          accA[mi][ni] =
              __builtin_amdgcn_mfma_f32_16x16x32_bf16(aF[mi], bFa[ni], accA[mi][ni], 0, 0, 0);
          accG[mi][ni] =
              __builtin_amdgcn_mfma_f32_16x16x32_bf16(aF[mi], bFg[ni], accG[mi][ni], 0, 0, 0);
        }
    }
    __syncthreads();
  }

#pragma unroll
  for (int mi = 0; mi < 4; ++mi) {
#pragma unroll
    for (int ni = 0; ni < 4; ++ni) {
      int ncol = n0 + wn + ni * 16 + fr;
      float ba = bias[ncol], bg = bias[ncol + 1024];
#pragma unroll
      for (int j = 0; j < 4; ++j) {
        int mrow = m0 + wm + mi * 16 + fg * 4 + j;
        float av = accA[mi][ni][j] + ba;
        float gv = accG[mi][ni][j] + bg;
        hpad[((size_t)b * HPRA + PADW + mrow) * CONV_INNER + ncol] =
            (bf16)(av * fsigmoid(gv));
      }
    }
  }
}

// ---------------------------------------------------------------- conv GEMM v9
// v8 continuous pipeline + 32x32x16 MFMA (17% fewer matrix-pipe cycles,
// identical LDS traffic). 64x64 wave tile = 2x2 tiles of 32x32.
// A-frag: row=lane&31, k=(lane>>5)*8+j ; C/D: col=lane&31,
// row=(reg&3)+8*(reg>>2)+4*(lane>>5).
__global__ __launch_bounds__(256) void k_conv(const bf16* __restrict__ hpad,
                                              const bf16* __restrict__ wt,
                                              const float* __restrict__ bias,
                                              const float* __restrict__ g,
                                              const float* __restrict__ bb,
                                              bf16* __restrict__ outb) {
  __shared__ __align__(16) bf16 sA0[160 * 64];     // 20 KB
  __shared__ __align__(16) bf16 sA1[160 * 64];     // 20 KB
  __shared__ __align__(16) bf16 sB0[128 * 64];     // 16 KB
  __shared__ __align__(16) bf16 sB1[128 * 64];     // 16 KB
  const int tid = threadIdx.x;
  const int b = blockIdx.z;
  const int n0 = blockIdx.x * 128, m0 = blockIdx.y * 128;
  const int lane = tid & 63, wid = tid >> 6;
  const int wm = (wid & 1) * 64, wn = (wid >> 1) * 64;
  const int l31 = lane & 31, lh = lane >> 5;      // row-in-tile, k-half
  const int srow = lane >> 3;
  const int scol = ((lane & 7) ^ srow) * 8;
  const size_t WKS = (size_t)CONV_INNER * CONV_INNER;

  f32x16 acc[2][2];
#pragma unroll
  for (int i = 0; i < 2; ++i)
#pragma unroll
    for (int j = 0; j < 2; ++j) acc[i][j] = (f32x16)0.f;

  const bf16* Abase = hpad + ((size_t)b * HPRA + m0 + srow) * CONV_INNER + scol;
  const bf16* Wbase = wt + (size_t)(n0 + srow) * CONV_INNER + scol;

  bf16* aCur = sA0; bf16* aNxt = sA1;
  bf16* bCur = sB0; bf16* bNxt = sB1;

  // prologue: A(0), B(0,0)
#pragma unroll
  for (int c = 0; c < 5; ++c) {
    const int ch = wid + c * 4;
    gld16(Abase + (size_t)(ch * 8) * CONV_INNER, &aCur[ch * 512]);
  }
#pragma unroll
  for (int c = 0; c < 4; ++c) {
    const int ch = wid + c * 4;
    gld16(Wbase + (size_t)(ch * 8) * CONV_INNER, &bCur[ch * 512]);
  }
  __syncthreads();

  for (int it = 0; it < 16; ++it) {
    const int itc = it * 64;
    for (int ks = 0; ks < KW; ++ks) {
      if (ks + 1 < KW) {
#pragma unroll
        for (int c = 0; c < 4; ++c) {
          const int ch = wid + c * 4;
          gld16(Wbase + (size_t)(ks + 1) * WKS + (size_t)(ch * 8) * CONV_INNER + itc,
                &bNxt[ch * 512]);
        }
      } else if (it + 1 < 16) {
#pragma unroll
        for (int c = 0; c < 4; ++c) {
          const int ch = wid + c * 4;
          gld16(Wbase + (size_t)(ch * 8) * CONV_INNER + itc + 64, &bNxt[ch * 512]);
        }
      }
      if (ks == KW - 2 && it + 1 < 16) {
#pragma unroll
        for (int c = 0; c < 5; ++c) {
          const int ch = wid + c * 4;
          gld16(Abase + (size_t)(ch * 8) * CONV_INNER + itc + 64, &aNxt[ch * 512]);
        }
      }
#pragma unroll
      for (int s = 0; s < 4; ++s) {
        const int cg = s * 2 + lh;
        bf16x8 aF[2], bF[2];
#pragma unroll
        for (int t = 0; t < 2; ++t) {
          const int ar = ks + wm + t * 32 + l31;
          aF[t] = *reinterpret_cast<const bf16x8*>(
              &aCur[ar * 64 + ((cg ^ (ar & 7)) * 8)]);
          const int br = wn + t * 32 + l31;
          bF[t] = *reinterpret_cast<const bf16x8*>(
              &bCur[br * 64 + ((cg ^ (br & 7)) * 8)]);
        }
#pragma unroll
        for (int ti = 0; ti < 2; ++ti)
#pragma unroll
          for (int tj = 0; tj < 2; ++tj)
            acc[ti][tj] = __builtin_amdgcn_mfma_f32_32x32x16_bf16(aF[ti], bF[tj],
                                                                  acc[ti][tj], 0, 0, 0);
      }
      __syncthreads();
      bf16* t = bCur; bCur = bNxt; bNxt = t;
    }
    bf16* t = aCur; aCur = aNxt; aNxt = t;
  }

#pragma unroll
  for (int ti = 0; ti < 2; ++ti) {
#pragma unroll
    for (int tj = 0; tj < 2; ++tj) {
      int ncol = n0 + wn + tj * 32 + l31;
      float bv = bias[ncol], gg = g[ncol], bbv = bb[ncol];
#pragma unroll
      for (int reg = 0; reg < 16; ++reg) {
        int mrow = m0 + wm + ti * 32 + (reg & 3) + 8 * (reg >> 2) + 4 * lh;
        float a = acc[ti][tj][reg] + bv;
        outb[((size_t)b * SEQ + mrow) * CONV_INNER + ncol] = (bf16)fsilu(a * gg + bbv);
      }
    }
  }
}

// ---------------------------------------------------------------- flash attention
__global__ __launch_bounds__(256) void k_attn(const bf16* __restrict__ qkv,
                                              const bf16* __restrict__ vT,
                                              bf16* __restrict__ out) {
  __shared__ __align__(16) bf16 sQ[128][72];
  __shared__ __align__(16) bf16 sK[64][72];
  __shared__ __align__(16) bf16 sVT[64][72];
  __shared__ __align__(16) bf16 sP[128][72];
  const int tid = threadIdx.x;
  const int bh = blockIdx.y;
  const int b = bh >> 3, h = bh & 7;
  const int m0 = blockIdx.x * 128;
  const int lane = tid & 63, wid = tid >> 6;
  const int w32 = wid * 32;
  const int fr = lane & 15, fg = lane >> 4;
  const size_t base = (size_t)b * SEQ * 1536;
  const size_t vbase = (size_t)bh * 64 * SEQ;

  for (int idx = tid; idx < 128 * 8; idx += 256) {
    int row = idx >> 3, c = (idx & 7) * 8;
    *reinterpret_cast<uint4v*>(&sQ[row][c]) =
        *reinterpret_cast<const uint4v*>(qkv + base + (size_t)(m0 + row) * 1536 + h * 64 + c);
  }

  f32x4 o[2][4];
  float mst[2][4], lst[2][4];
#pragma unroll
  for (int mi = 0; mi < 2; ++mi)
#pragma unroll
    for (int j = 0; j < 4; ++j) {
      mst[mi][j] = -1e30f;
      lst[mi][j] = 0.f;
#pragma unroll
      for (int df = 0; df < 4; ++df) o[mi][df] = (f32x4)0.f;
    }

  for (int t0 = 0; t0 < SEQ; t0 += 64) {
    for (int idx = tid; idx < 64 * 8; idx += 256) {
      int row = idx >> 3, c = (idx & 7) * 8;
      *reinterpret_cast<uint4v*>(&sK[row][c]) = *reinterpret_cast<const uint4v*>(
          qkv + base + (size_t)(t0 + row) * 1536 + 512 + h * 64 + c);
      *reinterpret_cast<uint4v*>(&sVT[row][c]) = *reinterpret_cast<const uint4v*>(
          vT + vbase + (size_t)row * SEQ + t0 + c);
    }
    __syncthreads();

    f32x4 sacc[2][4];
#pragma unroll
    for (int mi = 0; mi < 2; ++mi)
#pragma unroll
      for (int tf = 0; tf < 4; ++tf) sacc[mi][tf] = (f32x4)0.f;
#pragma unroll
    for (int kk = 0; kk < 2; ++kk) {
      bf16x8 aQ[2], bK[4];
#pragma unroll
      for (int mi = 0; mi < 2; ++mi)
        aQ[mi] = *reinterpret_cast<const bf16x8*>(&sQ[w32 + mi * 16 + fr][kk * 32 + fg * 8]);
#pragma unroll
      for (int tf = 0; tf < 4; ++tf)
        bK[tf] = *reinterpret_cast<const bf16x8*>(&sK[tf * 16 + fr][kk * 32 + fg * 8]);
#pragma unroll
      for (int mi = 0; mi < 2; ++mi)
#pragma unroll
        for (int tf = 0; tf < 4; ++tf)
          sacc[mi][tf] =
              __builtin_amdgcn_mfma_f32_16x16x32_bf16(aQ[mi], bK[tf], sacc[mi][tf], 0, 0, 0);
    }

#pragma unroll
    for (int mi = 0; mi < 2; ++mi) {
#pragma unroll
      for (int j = 0; j < 4; ++j) {
        float rm = -1e30f;
#pragma unroll
        for (int tf = 0; tf < 4; ++tf) rm = fmaxf(rm, sacc[mi][tf][j] * 0.125f);
#pragma unroll
        for (int off = 1; off < 16; off <<= 1) rm = fmaxf(rm, __shfl_xor(rm, off));
        float mnew = fmaxf(mst[mi][j], rm);
        float al = __expf(mst[mi][j] - mnew);
        float ps = 0.f;
#pragma unroll
        for (int tf = 0; tf < 4; ++tf) {
          float p = __expf(sacc[mi][tf][j] * 0.125f - mnew);
          ps += p;
          sP[w32 + mi * 16 + fg * 4 + j][tf * 16 + fr] = (bf16)p;
        }
#pragma unroll
        for (int off = 1; off < 16; off <<= 1) ps += __shfl_xor(ps, off);
        lst[mi][j] = lst[mi][j] * al + ps;
        mst[mi][j] = mnew;
#pragma unroll
        for (int df = 0; df < 4; ++df) o[mi][df][j] *= al;
      }
    }
    __syncthreads();

#pragma unroll
    for (int kk = 0; kk < 2; ++kk) {
      bf16x8 aP[2], bV[4];
#pragma unroll
      for (int mi = 0; mi < 2; ++mi)
        aP[mi] = *reinterpret_cast<const bf16x8*>(&sP[w32 + mi * 16 + fr][kk * 32 + fg * 8]);
#pragma unroll
      for (int df = 0; df < 4; ++df)
        bV[df] = *reinterpret_cast<const bf16x8*>(&sVT[df * 16 + fr][kk * 32 + fg * 8]);
#pragma unroll
      for (int mi = 0; mi < 2; ++mi)
#pragma unroll
        for (int df = 0; df < 4; ++df)
          o[mi][df] = __builtin_amdgcn_mfma_f32_16x16x32_bf16(aP[mi], bV[df], o[mi][df], 0, 0, 0);
    }
    __syncthreads();
  }

#pragma unroll
  for (int mi = 0; mi < 2; ++mi)
#pragma unroll
    for (int df = 0; df < 4; ++df)
#pragma unroll
      for (int j = 0; j < 4; ++j) {
        int row = m0 + w32 + mi * 16 + fg * 4 + j;
        int col = h * 64 + df * 16 + fr;
        out[((size_t)b * SEQ + row) * 512 + col] = (bf16)(o[mi][df][j] / lst[mi][j]);
      }
}

// ---------------------------------------------------------------- launcher

extern "C" void kernel_launch(void* const* d_in, const int* in_sizes, int n_in,
                              void* d_out, int out_size, void* d_ws, size_t ws_size,
                              hipStream_t stream) {
  const float* x      = (const float*)d_in[0];
  const float* ff1_g  = (const float*)d_in[1];
  const float* ff1_b  = (const float*)d_in[2];
  const float* ff1_w1 = (const float*)d_in[3];
  const float* ff1_b1 = (const float*)d_in[4];
  const float* ff1_w2 = (const float*)d_in[5];
  const float* ff1_b2 = (const float*)d_in[6];
  const float* attn_g = (const float*)d_in[7];
  const float* attn_b = (const float*)d_in[8];
  const float* wq     = (const float*)d_in[9];
  const float* bq     = (const float*)d_in[10];
  const float* wk     = (const float*)d_in[11];
  const float* bk     = (const float*)d_in[12];
  const float* wv     = (const float*)d_in[13];
  const float* bv     = (const float*)d_in[14];
  const float* wo     = (const float*)d_in[15];
  const float* bo     = (const float*)d_in[16];
  const float* conv_g = (const float*)d_in[17];
  const float* conv_b = (const float*)d_in[18];
  const float* pw1_w  = (const float*)d_in[19];
  const float* pw1_b  = (const float*)d_in[20];
  const float* dconv_w = (const float*)d_in[21];
  const float* dconv_b = (const float*)d_in[22];
  const float* cbn_g  = (const float*)d_in[23];
  const float* cbn_b  = (const float*)d_in[24];
  const float* pw2_w  = (const float*)d_in[25];
  const float* pw2_b  = (const float*)d_in[26];
  const float* ff2_g  = (const float*)d_in[27];
  const float* ff2_b  = (const float*)d_in[28];
  const float* ff2_w1 = (const float*)d_in[29];
  const float* ff2_b1 = (const float*)d_in[30];
  const float* ff2_w2 = (const float*)d_in[31];
  const float* ff2_b2 = (const float*)d_in[32];
  const float* fin_g  = (const float*)d_in[33];
  const float* fin_b  = (const float*)d_in[34];

  char* ws = (char*)d_ws;
  size_t off = 0;
  auto alloc = [&](size_t bytes) -> void* {
    off = (off + 255) & ~(size_t)255;
    void* p = ws + off;
    off += bytes;
    return p;
  };

  // ---- persistent small weights (~9.4 MB)
  bf16* wqkv  = (bf16*)alloc((size_t)1536 * 512 * 2);
  float* qkvb = (float*)alloc(1536 * 4);
  bf16* wf1a  = (bf16*)alloc((size_t)1024 * 512 * 2);
  bf16* wf1b  = (bf16*)alloc((size_t)512 * 1024 * 2);
  bf16* wwo   = (bf16*)alloc((size_t)512 * 512 * 2);
  bf16* wpw1  = (bf16*)alloc((size_t)2048 * 512 * 2);
  bf16* wpw2  = (bf16*)alloc((size_t)512 * 1024 * 2);
  bf16* wf2a  = (bf16*)alloc((size_t)1024 * 512 * 2);
  bf16* wf2b  = (bf16*)alloc((size_t)512 * 1024 * 2);

  // ---- persistent activation buffers
  bf16*  Bn  = (bf16*)alloc((size_t)NB * SEQ * 512 * 2);    // 8MB
  float* F1  = (float*)alloc((size_t)NB * SEQ * 512 * 4);   // 16MB
  bf16*  HGp = (bf16*)alloc((size_t)NB * HPRA * 1024 * 2);  // 17.3MB
  bf16*  H2  = (bf16*)alloc((size_t)NB * SEQ * 1024 * 2);   // 16MB

  // ---- big region E (62MB)
  char* E = (char*)alloc((size_t)KW * 1024 * 1024 * 2);
  bf16*  wt     = (bf16*)E;
  bf16*  h1     = (bf16*)E;
  bf16*  qkv    = (bf16*)E;
  bf16*  attn_o = (bf16*)(E + (size_t)24 * 1024 * 1024);
  float* x1     = (float*)(E + (size_t)32 * 1024 * 1024);
  bf16*  vT     = (bf16*)(E + (size_t)48 * 1024 * 1024);
  float* x3     = (float*)E;
  bf16*  h3     = (bf16*)(E + (size_t)16 * 1024 * 1024);

  float* xT = F1;
  float* x2 = F1;
  bf16* xbn = Bn, *x1bn = Bn, *x2bn = Bn, *x3bn = Bn;
  size_t needed = off;
  (void)in_sizes; (void)n_in;

  if (ws_size < needed) {
    k_diag<<<(out_size + 255) / 256, 256, 0, stream>>>(
        (float*)d_out, out_size, (float)(ws_size >> 20));
    return;
  }

  // ---- weight prep: one fused conversion launch (10 segments)
  CvtArgs ca;
  ca.s[0] = wq;      ca.d[0] = wqkv;
  ca.s[1] = wk;      ca.d[1] = wqkv + 512 * 512;
  ca.s[2] = wv;      ca.d[2] = wqkv + 1024 * 512;
  ca.s[3] = ff1_w1;  ca.d[3] = wf1a;
  ca.s[4] = ff1_w2;  ca.d[4] = wf1b;
  ca.s[5] = wo;      ca.d[5] = wwo;
  ca.s[6] = pw1_w;   ca.d[6] = wpw1;
  ca.s[7] = pw2_w;   ca.d[7] = wpw2;
  ca.s[8] = ff2_w1;  ca.d[8] = wf2a;
  ca.s[9] = ff2_w2;  ca.d[9] = wf2b;
  int blocks1024[10] = {256, 256, 256, 512, 512, 256, 1024, 512, 512, 512};
  int cum = 0;
  for (int i = 0; i < 10; ++i) { ca.cum[i] = cum; cum += blocks1024[i]; }
  ca.cum[10] = cum;
  k_convert_all<<<cum, 256, 0, stream>>>(ca);
  k_concat_bias<<<6, 256, 0, stream>>>(bq, bk, bv, qkvb);
  k_pad_zero<<<(NB * 32 * 128) / 256, 256, 0, stream>>>(HGp);
  k_transpose_in<<<dim3(32, 16, NB), 256, 0, stream>>>(x, ff1_g, ff1_b, xT, xbn);

  // ---- FF1
  k_gemm<0><<<dim3(8, 8, NB), 256, 0, stream>>>(xbn, wf1a, ff1_b1, nullptr, nullptr,
                                                nullptr, nullptr, h1, nullptr, 1024, 512);
  k_gemm<1><<<dim3(4, 8, NB), 256, 0, stream>>>(h1, wf1b, ff1_b2, xT, attn_g, attn_b,
                                                x1, x1bn, nullptr, 512, 1024);
  // ---- attention
  k_gemm<6><<<dim3(12, 8, NB), 256, 0, stream>>>(x1bn, wqkv, qkvb, nullptr, nullptr,
                                                 nullptr, nullptr, qkv, vT, 1536, 512);
  k_attn<<<dim3(8, 64), 256, 0, stream>>>(qkv, vT, attn_o);
  k_gemm<3><<<dim3(4, 8, NB), 256, 0, stream>>>(attn_o, wwo, bo, x1, conv_g, conv_b,
                                                x2, x2bn, nullptr, 512, 512);
  // ---- conv weight transform (E free now)
  k_conv_wt<<<dim3(1024, 4), 256, 0, stream>>>(dconv_w, wt);
  // ---- conv module
  k_pw1_glu<<<dim3(8, 8, NB), 256, 0, stream>>>(x2bn, wpw1, pw1_b, HGp);
  k_conv<<<dim3(8, 8, NB), 256, 0, stream>>>(HGp, wt, dconv_b, cbn_g, cbn_b, H2);
  // (wt dead now -> x3/h3 reuse E)
  k_gemm<3><<<dim3(4, 8, NB), 256, 0, stream>>>(H2, wpw2, pw2_b, x2, ff2_g, ff2_b,
                                                x3, x3bn, nullptr, 512, 1024);
  // ---- FF2 + final BN (transposed store to d_out)
  k_gemm<0><<<dim3(8, 8, NB), 256, 0, stream>>>(x3bn, wf2a, ff2_b1, nullptr, nullptr,
                                                nullptr, nullptr, h3, nullptr, 1024, 512);
  k_gemm<5><<<dim3(4, 8, NB), 256, 0, stream>>>(h3, wf2b, ff2_b2, x3, fin_g, fin_b,
                                                (float*)d_out, nullptr, nullptr, 512, 1024);
}

// Round 18
// 760.872 us; speedup vs baseline: 1.0636x; 1.0636x over previous
//
#include <hip/hip_runtime.h>
#include <cstdint>
#include <cstddef>

using bf16 = __bf16;
typedef __bf16 bf16x8 __attribute__((ext_vector_type(8)));
typedef float f32x4 __attribute__((ext_vector_type(4)));
typedef unsigned int uint4v __attribute__((ext_vector_type(4)));

#define NB 8       // batch
#define DIM 512
#define SEQ 1024
#define NH 8
#define DH 64
#define CONV_INNER 1024
#define KW 31
#define PADW 15
#define HPRA 1056

__device__ __forceinline__ float fsigmoid(float x) { return 1.f / (1.f + __expf(-x)); }
__device__ __forceinline__ float fsilu(float x) { return x * fsigmoid(x); }

__device__ __forceinline__ void gld16(const bf16* g, bf16* l) {
  __builtin_amdgcn_global_load_lds(
      (const __attribute__((address_space(1))) unsigned int*)g,
      (__attribute__((address_space(3))) unsigned int*)l, 16, 0, 0);
}

// ---------------------------------------------------------------- ws guard

__global__ __launch_bounds__(256) void k_diag(float* __restrict__ out, int n, float v) {
  int i = blockIdx.x * 256 + threadIdx.x;
  if (i < n) out[i] = v;
}

// ---------------------------------------------------------------- prep kernels

struct CvtArgs {
  const float* s[10];
  bf16* d[10];
  int cum[11];
};

__global__ __launch_bounds__(256) void k_convert_all(CvtArgs a) {
  int blk = blockIdx.x;
  int seg = 0;
#pragma unroll
  for (int t = 0; t < 10; ++t)
    if (blk >= a.cum[t + 1]) seg = t + 1;
  const float* src = a.s[seg];
  bf16* dst = a.d[seg];
  int i = ((blk - a.cum[seg]) * 256 + threadIdx.x) * 4;
  float4 v = *reinterpret_cast<const float4*>(src + i);
  dst[i]     = (bf16)v.x;
  dst[i + 1] = (bf16)v.y;
  dst[i + 2] = (bf16)v.z;
  dst[i + 3] = (bf16)v.w;
}

// dconv_w [O=1024][I=1024][K=31] fp32 -> wt [k][o][i] bf16 (vectorized 16B stores)
__global__ __launch_bounds__(256) void k_conv_wt(const float* __restrict__ w,
                                                 bf16* __restrict__ wt) {
  __shared__ float t[256 * KW];   // [i_local][k]
  int o = blockIdx.x, i0 = blockIdx.y * 256;
  const float* src = w + (size_t)o * (CONV_INNER * KW) + (size_t)i0 * KW;
  for (int idx = threadIdx.x; idx < 256 * KW; idx += 256) t[idx] = src[idx];
  __syncthreads();
  for (int idx = threadIdx.x; idx < KW * 32; idx += 256) {
    int k = idx >> 5, c = idx & 31;
    bf16x8 v;
#pragma unroll
    for (int e = 0; e < 8; ++e) v[e] = (bf16)t[(c * 8 + e) * KW + k];
    *reinterpret_cast<bf16x8*>(
        &wt[((size_t)k * CONV_INNER + o) * CONV_INNER + i0 + c * 8]) = v;
  }
}

__global__ __launch_bounds__(256) void k_pad_zero(bf16* __restrict__ hpad) {
  int i = blockIdx.x * 256 + threadIdx.x;
  int b = i / (32 * 128);
  int r = (i >> 7) & 31;
  int c8 = (i & 127) * 8;
  int row = (r < PADW) ? r : 1024 + r;
  uint4v z = {0u, 0u, 0u, 0u};
  *reinterpret_cast<uint4v*>(&hpad[((size_t)b * HPRA + row) * CONV_INNER + c8]) = z;
}

__global__ __launch_bounds__(256) void k_transpose_in(const float* __restrict__ x,
                                                      const float* __restrict__ g,
                                                      const float* __restrict__ bvec,
                                                      float* __restrict__ xT,
                                                      bf16* __restrict__ xbn) {
  __shared__ float t[32][33];
  int s0 = blockIdx.x * 32, c0 = blockIdx.y * 32, b = blockIdx.z;
  int col = threadIdx.x & 31, rq = threadIdx.x >> 5;
#pragma unroll
  for (int i = 0; i < 4; ++i) {
    int row = rq + i * 8;
    t[row][col] = x[((size_t)b * DIM + c0 + row) * SEQ + s0 + col];
  }
  __syncthreads();
  float gg = g[c0 + col], bb = bvec[c0 + col];
#pragma unroll
  for (int i = 0; i < 4; ++i) {
    int srow = rq + i * 8;
    float v = t[col][srow];
    size_t off = ((size_t)b * SEQ + s0 + srow) * DIM + c0 + col;
    xT[off] = v;
    xbn[off] = (bf16)(v * gg + bb);
  }
}

__global__ __launch_bounds__(256) void k_concat_bias(const float* __restrict__ bq,
                                                     const float* __restrict__ bk,
                                                     const float* __restrict__ bv,
                                                     float* __restrict__ qb) {
  int i = blockIdx.x * 256 + threadIdx.x;
  if (i < 512) qb[i] = bq[i];
  else if (i < 1024) qb[i] = bk[i - 512];
  else if (i < 1536) qb[i] = bv[i - 1024];
}

// ---------------------------------------------------------------- generic GEMM v2
// Epilogues: 0 silu->bf16 | 1 res+0.5a, BN | 2 bf16 | 3 res+a, BN | 5 final BN
// transposed | 6 qkv: Q,K -> outb; V -> vtout transposed [bh][d][s]
template <int EPI>
__global__ __launch_bounds__(256) void k_gemm(const bf16* __restrict__ A,
                                              const bf16* __restrict__ W,
                                              const float* __restrict__ bias,
                                              const float* __restrict__ res,
                                              const float* __restrict__ g,
                                              const float* __restrict__ bb,
                                              float* __restrict__ outf,
                                              bf16* __restrict__ outb,
                                              bf16* __restrict__ vtout, int N, int K) {
  __shared__ __align__(16) bf16 sA[2][128 * 64];
  __shared__ __align__(16) bf16 sB[2][128 * 64];
  const int tid = threadIdx.x;
  const int b = blockIdx.z;
  const int m0 = blockIdx.y * 128, n0 = blockIdx.x * 128;
  const int lane = tid & 63, wid = tid >> 6;
  const int wm = (wid & 1) * 64, wn = (wid >> 1) * 64;
  const int fr = lane & 15, fg = lane >> 4;
  const int srow = lane >> 3;
  const int scol = ((lane & 7) ^ srow) * 8;

  f32x4 acc[4][4];
#pragma unroll
  for (int i = 0; i < 4; ++i)
#pragma unroll
    for (int j = 0; j < 4; ++j) acc[i][j] = (f32x4)0.f;

  const bf16* Abase = A + ((size_t)b * SEQ + m0 + srow) * K + scol;
  const bf16* Wbase = W + (size_t)(n0 + srow) * K + scol;
  const int nch = K >> 6;

#pragma unroll
  for (int c = 0; c < 4; ++c) {
    const int ch = wid + c * 4;
    gld16(Abase + (size_t)(ch * 8) * K, &sA[0][ch * 512]);
    gld16(Wbase + (size_t)(ch * 8) * K, &sB[0][ch * 512]);
  }
  __syncthreads();

  int buf = 0;
  for (int kt = 0; kt < nch; ++kt) {
    if (kt + 1 < nch) {
      const int kc = (kt + 1) * 64;
#pragma unroll
      for (int c = 0; c < 4; ++c) {
        const int ch = wid + c * 4;
        gld16(Abase + (size_t)(ch * 8) * K + kc, &sA[buf ^ 1][ch * 512]);
        gld16(Wbase + (size_t)(ch * 8) * K + kc, &sB[buf ^ 1][ch * 512]);
      }
    }
#pragma unroll
    for (int kk = 0; kk < 2; ++kk) {
      const int cg = kk * 4 + fg;
      bf16x8 aF[4], bF[4];
#pragma unroll
      for (int i = 0; i < 4; ++i) {
        const int ar = wm + i * 16 + fr;
        aF[i] = *reinterpret_cast<const bf16x8*>(
            &sA[buf][ar * 64 + ((cg ^ (ar & 7)) * 8)]);
        const int br = wn + i * 16 + fr;
        bF[i] = *reinterpret_cast<const bf16x8*>(
            &sB[buf][br * 64 + ((cg ^ (br & 7)) * 8)]);
      }
#pragma unroll
      for (int mi = 0; mi < 4; ++mi)
#pragma unroll
        for (int ni = 0; ni < 4; ++ni)
          acc[mi][ni] = __builtin_amdgcn_mfma_f32_16x16x32_bf16(aF[mi], bF[ni],
                                                                acc[mi][ni], 0, 0, 0);
    }
    __syncthreads();
    buf ^= 1;
  }

#pragma unroll
  for (int mi = 0; mi < 4; ++mi) {
#pragma unroll
    for (int ni = 0; ni < 4; ++ni) {
      int ncol = n0 + wn + ni * 16 + fr;
      float bv = bias[ncol];
      if constexpr (EPI == 5) {
        float gg = g[ncol], bbv = bb[ncol];
        int mrow0 = m0 + wm + mi * 16 + fg * 4;
        float v[4];
#pragma unroll
        for (int j = 0; j < 4; ++j) {
          float a = acc[mi][ni][j] + bv;
          float r = res[((size_t)b * SEQ + mrow0 + j) * 512 + ncol] + 0.5f * a;
          v[j] = r * gg + bbv;
        }
        *reinterpret_cast<float4*>(outf + ((size_t)b * 512 + ncol) * SEQ + mrow0) =
            make_float4(v[0], v[1], v[2], v[3]);
      } else {
#pragma unroll
        for (int j = 0; j < 4; ++j) {
          int mrow = m0 + wm + mi * 16 + fg * 4 + j;
          size_t off = ((size_t)b * SEQ + mrow) * N + ncol;
          float a = acc[mi][ni][j] + bv;
          if constexpr (EPI == 0) {
            outb[off] = (bf16)fsilu(a);
          } else if constexpr (EPI == 2) {
            outb[off] = (bf16)a;
          } else if constexpr (EPI == 6) {
            if (ncol < 1024) {
              outb[off] = (bf16)a;
            } else {
              int d = ncol - 1024;
              vtout[(((size_t)b * 8 + (d >> 6)) * 64 + (d & 63)) * SEQ + mrow] =
                  (bf16)a;
            }
          } else if constexpr (EPI == 1) {
            float r = res[off] + 0.5f * a;
            outf[off] = r;
            outb[off] = (bf16)(r * g[ncol] + bb[ncol]);
          } else if constexpr (EPI == 3) {
            float r = res[off] + a;
            outf[off] = r;
            outb[off] = (bf16)(r * g[ncol] + bb[ncol]);
          }
        }
      }
    }
  }
}

// ---------------------------------------------------------------- pw1 + GLU fused v2
__global__ __launch_bounds__(256) void k_pw1_glu(const bf16* __restrict__ A,
                                                 const bf16* __restrict__ W,
                                                 const float* __restrict__ bias,
                                                 bf16* __restrict__ hpad) {
  __shared__ __align__(16) bf16 sA[128 * 64];
  __shared__ __align__(16) bf16 sBa[128 * 64];
  __shared__ __align__(16) bf16 sBg[128 * 64];
  const int tid = threadIdx.x;
  const int b = blockIdx.z;
  const int m0 = blockIdx.y * 128, n0 = blockIdx.x * 128;
  const int lane = tid & 63, wid = tid >> 6;
  const int wm = (wid & 1) * 64, wn = (wid >> 1) * 64;
  const int fr = lane & 15, fg = lane >> 4;
  const int srow = lane >> 3;
  const int scol = ((lane & 7) ^ srow) * 8;
  const int K = 512;

  f32x4 accA[4][4], accG[4][4];
#pragma unroll
  for (int i = 0; i < 4; ++i)
#pragma unroll
    for (int j = 0; j < 4; ++j) { accA[i][j] = (f32x4)0.f; accG[i][j] = (f32x4)0.f; }

  const bf16* Abase = A + ((size_t)b * SEQ + m0 + srow) * K + scol;
  const bf16* WaB = W + (size_t)(n0 + srow) * K + scol;
  const bf16* WgB = W + (size_t)(n0 + 1024 + srow) * K + scol;

  for (int kt = 0; kt < 8; ++kt) {
    const int kc = kt * 64;
#pragma unroll
    for (int c = 0; c < 4; ++c) {
      const int ch = wid + c * 4;
      gld16(Abase + (size_t)(ch * 8) * K + kc, &sA[ch * 512]);
      gld16(WaB + (size_t)(ch * 8) * K + kc, &sBa[ch * 512]);
      gld16(WgB + (size_t)(ch * 8) * K + kc, &sBg[ch * 512]);
    }
    __syncthreads();
#pragma unroll
    for (int kk = 0; kk < 2; ++kk) {
      const int cg = kk * 4 + fg;
      bf16x8 aF[4], bFa[4], bFg[4];
#pragma unroll
      for (int i = 0; i < 4; ++i) {
        const int ar = wm + i * 16 + fr;
        aF[i] = *reinterpret_cast<const bf16x8*>(
            &sA[ar * 64 + ((cg ^ (ar & 7)) * 8)]);
        const int br = wn + i * 16 + fr;
        bFa[i] = *reinterpret_cast<const bf16x8*>(
            &sBa[br * 64 + ((cg ^ (br & 7)) * 8)]);
        bFg[i] = *reinterpret_cast<const bf16x8*>(
            &sBg[br * 64 + ((cg ^ (br & 7)) * 8)]);
      }
#pragma unroll
      for (int mi = 0; mi < 4; ++mi)
#pragma unroll
        for (int ni = 0; ni < 4; ++ni) {
          accA[mi][ni] =
              __builtin_amdgcn_mfma_f32_16x16x32_bf16(aF[mi], bFa[ni], accA[mi][ni], 0, 0, 0);
          accG[mi][ni] =
              __builtin_amdgcn_mfma_f32_16x16x32_bf16(aF[mi], bFg[ni], accG[mi][ni], 0, 0, 0);
        }
    }
    __syncthreads();
  }

#pragma unroll
  for (int mi = 0; mi < 4; ++mi) {
#pragma unroll
    for (int ni = 0; ni < 4; ++ni) {
      int ncol = n0 + wn + ni * 16 + fr;
      float ba = bias[ncol], bg = bias[ncol + 1024];
#pragma unroll
      for (int j = 0; j < 4; ++j) {
        int mrow = m0 + wm + mi * 16 + fg * 4 + j;
        float av = accA[mi][ni][j] + ba;
        float gv = accG[mi][ni][j] + bg;
        hpad[((size_t)b * HPRA + PADW + mrow) * CONV_INNER + ncol] =
            (bf16)(av * fsigmoid(gv));
      }
    }
  }
}

// ---------------------------------------------------------------- conv GEMM v8
// 128x128 block, 64x64 wave tile, K-chunk 64, XOR swizzle, A AND B double
// buffered with continuous cross-chunk pipeline. LDS 72 KB, 2 blocks/CU.
__global__ __launch_bounds__(256) void k_conv(const bf16* __restrict__ hpad,
                                              const bf16* __restrict__ wt,
                                              const float* __restrict__ bias,
                                              const float* __restrict__ g,
                                              const float* __restrict__ bb,
                                              bf16* __restrict__ outb) {
  __shared__ __align__(16) bf16 sA0[160 * 64];     // 20 KB
  __shared__ __align__(16) bf16 sA1[160 * 64];     // 20 KB
  __shared__ __align__(16) bf16 sB0[128 * 64];     // 16 KB
  __shared__ __align__(16) bf16 sB1[128 * 64];     // 16 KB
  const int tid = threadIdx.x;
  const int b = blockIdx.z;
  const int n0 = blockIdx.x * 128, m0 = blockIdx.y * 128;
  const int lane = tid & 63, wid = tid >> 6;
  const int wm = (wid & 1) * 64, wn = (wid >> 1) * 64;
  const int fr = lane & 15, fg = lane >> 4;
  const int srow = lane >> 3;
  const int scol = ((lane & 7) ^ srow) * 8;
  const size_t WKS = (size_t)CONV_INNER * CONV_INNER;

  f32x4 acc[4][4];
#pragma unroll
  for (int i = 0; i < 4; ++i)
#pragma unroll
    for (int j = 0; j < 4; ++j) acc[i][j] = (f32x4)0.f;

  const bf16* Abase = hpad + ((size_t)b * HPRA + m0 + srow) * CONV_INNER + scol;
  const bf16* Wbase = wt + (size_t)(n0 + srow) * CONV_INNER + scol;

  bf16* aCur = sA0; bf16* aNxt = sA1;
  bf16* bCur = sB0; bf16* bNxt = sB1;

  // prologue: A(0), B(0,0)
#pragma unroll
  for (int c = 0; c < 5; ++c) {
    const int ch = wid + c * 4;
    gld16(Abase + (size_t)(ch * 8) * CONV_INNER, &aCur[ch * 512]);
  }
#pragma unroll
  for (int c = 0; c < 4; ++c) {
    const int ch = wid + c * 4;
    gld16(Wbase + (size_t)(ch * 8) * CONV_INNER, &bCur[ch * 512]);
  }
  __syncthreads();

  for (int it = 0; it < 16; ++it) {
    const int itc = it * 64;
    for (int ks = 0; ks < KW; ++ks) {
      // B prefetch: next tap, or first tap of next chunk
      if (ks + 1 < KW) {
#pragma unroll
        for (int c = 0; c < 4; ++c) {
          const int ch = wid + c * 4;
          gld16(Wbase + (size_t)(ks + 1) * WKS + (size_t)(ch * 8) * CONV_INNER + itc,
                &bNxt[ch * 512]);
        }
      } else if (it + 1 < 16) {
#pragma unroll
        for (int c = 0; c < 4; ++c) {
          const int ch = wid + c * 4;
          gld16(Wbase + (size_t)(ch * 8) * CONV_INNER + itc + 64, &bNxt[ch * 512]);
        }
      }
      // A prefetch for next chunk while aNxt is idle
      if (ks == KW - 2 && it + 1 < 16) {
#pragma unroll
        for (int c = 0; c < 5; ++c) {
          const int ch = wid + c * 4;
          gld16(Abase + (size_t)(ch * 8) * CONV_INNER + itc + 64, &aNxt[ch * 512]);
        }
      }
#pragma unroll
      for (int kk = 0; kk < 2; ++kk) {
        const int cg = kk * 4 + fg;
        bf16x8 aF[4], bF[4];
#pragma unroll
        for (int i = 0; i < 4; ++i) {
          const int ar = ks + wm + i * 16 + fr;
          aF[i] = *reinterpret_cast<const bf16x8*>(
              &aCur[ar * 64 + ((cg ^ (ar & 7)) * 8)]);
        }
#pragma unroll
        for (int n = 0; n < 4; ++n) {
          const int br = wn + n * 16 + fr;
          bF[n] = *reinterpret_cast<const bf16x8*>(
              &bCur[br * 64 + ((cg ^ (br & 7)) * 8)]);
        }
#pragma unroll
        for (int mi = 0; mi < 4; ++mi)
#pragma unroll
          for (int ni = 0; ni < 4; ++ni)
            acc[mi][ni] = __builtin_amdgcn_mfma_f32_16x16x32_bf16(aF[mi], bF[ni],
                                                                  acc[mi][ni], 0, 0, 0);
      }
      __syncthreads();
      bf16* t = bCur; bCur = bNxt; bNxt = t;
    }
    bf16* t = aCur; aCur = aNxt; aNxt = t;
  }

#pragma unroll
  for (int mi = 0; mi < 4; ++mi) {
#pragma unroll
    for (int ni = 0; ni < 4; ++ni) {
      int ncol = n0 + wn + ni * 16 + fr;
      float bv = bias[ncol], gg = g[ncol], bbv = bb[ncol];
#pragma unroll
      for (int j = 0; j < 4; ++j) {
        int mrow = m0 + wm + mi * 16 + fg * 4 + j;
        float a = acc[mi][ni][j] + bv;
        outb[((size_t)b * SEQ + mrow) * CONV_INNER + ncol] = (bf16)fsilu(a * gg + bbv);
      }
    }
  }
}

// ---------------------------------------------------------------- flash attention
__global__ __launch_bounds__(256) void k_attn(const bf16* __restrict__ qkv,
                                              const bf16* __restrict__ vT,
                                              bf16* __restrict__ out) {
  __shared__ __align__(16) bf16 sQ[128][72];
  __shared__ __align__(16) bf16 sK[64][72];
  __shared__ __align__(16) bf16 sVT[64][72];
  __shared__ __align__(16) bf16 sP[128][72];
  const int tid = threadIdx.x;
  const int bh = blockIdx.y;
  const int b = bh >> 3, h = bh & 7;
  const int m0 = blockIdx.x * 128;
  const int lane = tid & 63, wid = tid >> 6;
  const int w32 = wid * 32;
  const int fr = lane & 15, fg = lane >> 4;
  const size_t base = (size_t)b * SEQ * 1536;
  const size_t vbase = (size_t)bh * 64 * SEQ;

  for (int idx = tid; idx < 128 * 8; idx += 256) {
    int row = idx >> 3, c = (idx & 7) * 8;
    *reinterpret_cast<uint4v*>(&sQ[row][c]) =
        *reinterpret_cast<const uint4v*>(qkv + base + (size_t)(m0 + row) * 1536 + h * 64 + c);
  }

  f32x4 o[2][4];
  float mst[2][4], lst[2][4];
#pragma unroll
  for (int mi = 0; mi < 2; ++mi)
#pragma unroll
    for (int j = 0; j < 4; ++j) {
      mst[mi][j] = -1e30f;
      lst[mi][j] = 0.f;
#pragma unroll
      for (int df = 0; df < 4; ++df) o[mi][df] = (f32x4)0.f;
    }

  for (int t0 = 0; t0 < SEQ; t0 += 64) {
    for (int idx = tid; idx < 64 * 8; idx += 256) {
      int row = idx >> 3, c = (idx & 7) * 8;
      *reinterpret_cast<uint4v*>(&sK[row][c]) = *reinterpret_cast<const uint4v*>(
          qkv + base + (size_t)(t0 + row) * 1536 + 512 + h * 64 + c);
      *reinterpret_cast<uint4v*>(&sVT[row][c]) = *reinterpret_cast<const uint4v*>(
          vT + vbase + (size_t)row * SEQ + t0 + c);
    }
    __syncthreads();

    f32x4 sacc[2][4];
#pragma unroll
    for (int mi = 0; mi < 2; ++mi)
#pragma unroll
      for (int tf = 0; tf < 4; ++tf) sacc[mi][tf] = (f32x4)0.f;
#pragma unroll
    for (int kk = 0; kk < 2; ++kk) {
      bf16x8 aQ[2], bK[4];
#pragma unroll
      for (int mi = 0; mi < 2; ++mi)
        aQ[mi] = *reinterpret_cast<const bf16x8*>(&sQ[w32 + mi * 16 + fr][kk * 32 + fg * 8]);
#pragma unroll
      for (int tf = 0; tf < 4; ++tf)
        bK[tf] = *reinterpret_cast<const bf16x8*>(&sK[tf * 16 + fr][kk * 32 + fg * 8]);
#pragma unroll
      for (int mi = 0; mi < 2; ++mi)
#pragma unroll
        for (int tf = 0; tf < 4; ++tf)
          sacc[mi][tf] =
              __builtin_amdgcn_mfma_f32_16x16x32_bf16(aQ[mi], bK[tf], sacc[mi][tf], 0, 0, 0);
    }

#pragma unroll
    for (int mi = 0; mi < 2; ++mi) {
#pragma unroll
      for (int j = 0; j < 4; ++j) {
        float rm = -1e30f;
#pragma unroll
        for (int tf = 0; tf < 4; ++tf) rm = fmaxf(rm, sacc[mi][tf][j] * 0.125f);
#pragma unroll
        for (int off = 1; off < 16; off <<= 1) rm = fmaxf(rm, __shfl_xor(rm, off));
        float mnew = fmaxf(mst[mi][j], rm);
        float al = __expf(mst[mi][j] - mnew);
        float ps = 0.f;
#pragma unroll
        for (int tf = 0; tf < 4; ++tf) {
          float p = __expf(sacc[mi][tf][j] * 0.125f - mnew);
          ps += p;
          sP[w32 + mi * 16 + fg * 4 + j][tf * 16 + fr] = (bf16)p;
        }
#pragma unroll
        for (int off = 1; off < 16; off <<= 1) ps += __shfl_xor(ps, off);
        lst[mi][j] = lst[mi][j] * al + ps;
        mst[mi][j] = mnew;
#pragma unroll
        for (int df = 0; df < 4; ++df) o[mi][df][j] *= al;
      }
    }
    __syncthreads();

#pragma unroll
    for (int kk = 0; kk < 2; ++kk) {
      bf16x8 aP[2], bV[4];
#pragma unroll
      for (int mi = 0; mi < 2; ++mi)
        aP[mi] = *reinterpret_cast<const bf16x8*>(&sP[w32 + mi * 16 + fr][kk * 32 + fg * 8]);
#pragma unroll
      for (int df = 0; df < 4; ++df)
        bV[df] = *reinterpret_cast<const bf16x8*>(&sVT[df * 16 + fr][kk * 32 + fg * 8]);
#pragma unroll
      for (int mi = 0; mi < 2; ++mi)
#pragma unroll
        for (int df = 0; df < 4; ++df)
          o[mi][df] = __builtin_amdgcn_mfma_f32_16x16x32_bf16(aP[mi], bV[df], o[mi][df], 0, 0, 0);
    }
    __syncthreads();
  }

#pragma unroll
  for (int mi = 0; mi < 2; ++mi)
#pragma unroll
    for (int df = 0; df < 4; ++df)
#pragma unroll
      for (int j = 0; j < 4; ++j) {
        int row = m0 + w32 + mi * 16 + fg * 4 + j;
        int col = h * 64 + df * 16 + fr;
        out[((size_t)b * SEQ + row) * 512 + col] = (bf16)(o[mi][df][j] / lst[mi][j]);
      }
}

// ---------------------------------------------------------------- launcher

extern "C" void kernel_launch(void* const* d_in, const int* in_sizes, int n_in,
                              void* d_out, int out_size, void* d_ws, size_t ws_size,
                              hipStream_t stream) {
  const float* x      = (const float*)d_in[0];
  const float* ff1_g  = (const float*)d_in[1];
  const float* ff1_b  = (const float*)d_in[2];
  const float* ff1_w1 = (const float*)d_in[3];
  const float* ff1_b1 = (const float*)d_in[4];
  const float* ff1_w2 = (const float*)d_in[5];
  const float* ff1_b2 = (const float*)d_in[6];
  const float* attn_g = (const float*)d_in[7];
  const float* attn_b = (const float*)d_in[8];
  const float* wq     = (const float*)d_in[9];
  const float* bq     = (const float*)d_in[10];
  const float* wk     = (const float*)d_in[11];
  const float* bk     = (const float*)d_in[12];
  const float* wv     = (const float*)d_in[13];
  const float* bv     = (const float*)d_in[14];
  const float* wo     = (const float*)d_in[15];
  const float* bo     = (const float*)d_in[16];
  const float* conv_g = (const float*)d_in[17];
  const float* conv_b = (const float*)d_in[18];
  const float* pw1_w  = (const float*)d_in[19];
  const float* pw1_b  = (const float*)d_in[20];
  const float* dconv_w = (const float*)d_in[21];
  const float* dconv_b = (const float*)d_in[22];
  const float* cbn_g  = (const float*)d_in[23];
  const float* cbn_b  = (const float*)d_in[24];
  const float* pw2_w  = (const float*)d_in[25];
  const float* pw2_b  = (const float*)d_in[26];
  const float* ff2_g  = (const float*)d_in[27];
  const float* ff2_b  = (const float*)d_in[28];
  const float* ff2_w1 = (const float*)d_in[29];
  const float* ff2_b1 = (const float*)d_in[30];
  const float* ff2_w2 = (const float*)d_in[31];
  const float* ff2_b2 = (const float*)d_in[32];
  const float* fin_g  = (const float*)d_in[33];
  const float* fin_b  = (const float*)d_in[34];

  char* ws = (char*)d_ws;
  size_t off = 0;
  auto alloc = [&](size_t bytes) -> void* {
    off = (off + 255) & ~(size_t)255;
    void* p = ws + off;
    off += bytes;
    return p;
  };

  // ---- persistent small weights (~9.4 MB)
  bf16* wqkv  = (bf16*)alloc((size_t)1536 * 512 * 2);
  float* qkvb = (float*)alloc(1536 * 4);
  bf16* wf1a  = (bf16*)alloc((size_t)1024 * 512 * 2);
  bf16* wf1b  = (bf16*)alloc((size_t)512 * 1024 * 2);
  bf16* wwo   = (bf16*)alloc((size_t)512 * 512 * 2);
  bf16* wpw1  = (bf16*)alloc((size_t)2048 * 512 * 2);
  bf16* wpw2  = (bf16*)alloc((size_t)512 * 1024 * 2);
  bf16* wf2a  = (bf16*)alloc((size_t)1024 * 512 * 2);
  bf16* wf2b  = (bf16*)alloc((size_t)512 * 1024 * 2);

  // ---- persistent activation buffers
  bf16*  Bn  = (bf16*)alloc((size_t)NB * SEQ * 512 * 2);    // 8MB
  float* F1  = (float*)alloc((size_t)NB * SEQ * 512 * 4);   // 16MB
  bf16*  HGp = (bf16*)alloc((size_t)NB * HPRA * 1024 * 2);  // 17.3MB
  bf16*  H2  = (bf16*)alloc((size_t)NB * SEQ * 1024 * 2);   // 16MB

  // ---- big region E (62MB)
  char* E = (char*)alloc((size_t)KW * 1024 * 1024 * 2);
  bf16*  wt     = (bf16*)E;
  bf16*  h1     = (bf16*)E;
  bf16*  qkv    = (bf16*)E;
  bf16*  attn_o = (bf16*)(E + (size_t)24 * 1024 * 1024);
  float* x1     = (float*)(E + (size_t)32 * 1024 * 1024);
  bf16*  vT     = (bf16*)(E + (size_t)48 * 1024 * 1024);
  float* x3     = (float*)E;
  bf16*  h3     = (bf16*)(E + (size_t)16 * 1024 * 1024);

  float* xT = F1;
  float* x2 = F1;
  bf16* xbn = Bn, *x1bn = Bn, *x2bn = Bn, *x3bn = Bn;
  size_t needed = off;
  (void)in_sizes; (void)n_in;

  if (ws_size < needed) {
    k_diag<<<(out_size + 255) / 256, 256, 0, stream>>>(
        (float*)d_out, out_size, (float)(ws_size >> 20));
    return;
  }

  // ---- weight prep: one fused conversion launch (10 segments)
  CvtArgs ca;
  ca.s[0] = wq;      ca.d[0] = wqkv;
  ca.s[1] = wk;      ca.d[1] = wqkv + 512 * 512;
  ca.s[2] = wv;      ca.d[2] = wqkv + 1024 * 512;
  ca.s[3] = ff1_w1;  ca.d[3] = wf1a;
  ca.s[4] = ff1_w2;  ca.d[4] = wf1b;
  ca.s[5] = wo;      ca.d[5] = wwo;
  ca.s[6] = pw1_w;   ca.d[6] = wpw1;
  ca.s[7] = pw2_w;   ca.d[7] = wpw2;
  ca.s[8] = ff2_w1;  ca.d[8] = wf2a;
  ca.s[9] = ff2_w2;  ca.d[9] = wf2b;
  int blocks1024[10] = {256, 256, 256, 512, 512, 256, 1024, 512, 512, 512};
  int cum = 0;
  for (int i = 0; i < 10; ++i) { ca.cum[i] = cum; cum += blocks1024[i]; }
  ca.cum[10] = cum;
  k_convert_all<<<cum, 256, 0, stream>>>(ca);
  k_concat_bias<<<6, 256, 0, stream>>>(bq, bk, bv, qkvb);
  k_pad_zero<<<(NB * 32 * 128) / 256, 256, 0, stream>>>(HGp);
  k_transpose_in<<<dim3(32, 16, NB), 256, 0, stream>>>(x, ff1_g, ff1_b, xT, xbn);

  // ---- FF1
  k_gemm<0><<<dim3(8, 8, NB), 256, 0, stream>>>(xbn, wf1a, ff1_b1, nullptr, nullptr,
                                                nullptr, nullptr, h1, nullptr, 1024, 512);
  k_gemm<1><<<dim3(4, 8, NB), 256, 0, stream>>>(h1, wf1b, ff1_b2, xT, attn_g, attn_b,
                                                x1, x1bn, nullptr, 512, 1024);
  // ---- attention
  k_gemm<6><<<dim3(12, 8, NB), 256, 0, stream>>>(x1bn, wqkv, qkvb, nullptr, nullptr,
                                                 nullptr, nullptr, qkv, vT, 1536, 512);
  k_attn<<<dim3(8, 64), 256, 0, stream>>>(qkv, vT, attn_o);
  k_gemm<3><<<dim3(4, 8, NB), 256, 0, stream>>>(attn_o, wwo, bo, x1, conv_g, conv_b,
                                                x2, x2bn, nullptr, 512, 512);
  // ---- conv weight transform (E free now)
  k_conv_wt<<<dim3(1024, 4), 256, 0, stream>>>(dconv_w, wt);
  // ---- conv module
  k_pw1_glu<<<dim3(8, 8, NB), 256, 0, stream>>>(x2bn, wpw1, pw1_b, HGp);
  k_conv<<<dim3(8, 8, NB), 256, 0, stream>>>(HGp, wt, dconv_b, cbn_g, cbn_b, H2);
  // (wt dead now -> x3/h3 reuse E)
  k_gemm<3><<<dim3(4, 8, NB), 256, 0, stream>>>(H2, wpw2, pw2_b, x2, ff2_g, ff2_b,
                                                x3, x3bn, nullptr, 512, 1024);
  // ---- FF2 + final BN (transposed store to d_out)
  k_gemm<0><<<dim3(8, 8, NB), 256, 0, stream>>>(x3bn, wf2a, ff2_b1, nullptr, nullptr,
                                                nullptr, nullptr, h3, nullptr, 1024, 512);
  k_gemm<5><<<dim3(4, 8, NB), 256, 0, stream>>>(h3, wf2b, ff2_b2, x3, fin_g, fin_b,
                                                (float*)d_out, nullptr, nullptr, 512, 1024);
}

// Round 19
// 756.433 us; speedup vs baseline: 1.0698x; 1.0059x over previous
//
#include <hip/hip_runtime.h>
#include <cstdint>
#include <cstddef>

using bf16 = __bf16;
typedef __bf16 bf16x8 __attribute__((ext_vector_type(8)));
typedef float f32x4 __attribute__((ext_vector_type(4)));
typedef unsigned int uint4v __attribute__((ext_vector_type(4)));

#define NB 8       // batch
#define DIM 512
#define SEQ 1024
#define NH 8
#define DH 64
#define CONV_INNER 1024
#define KW 31
#define PADW 15
#define HPRA 1056

__device__ __forceinline__ float fsigmoid(float x) { return 1.f / (1.f + __expf(-x)); }
__device__ __forceinline__ float fsilu(float x) { return x * fsigmoid(x); }

__device__ __forceinline__ void gld16(const bf16* g, bf16* l) {
  __builtin_amdgcn_global_load_lds(
      (const __attribute__((address_space(1))) unsigned int*)g,
      (__attribute__((address_space(3))) unsigned int*)l, 16, 0, 0);
}

// ---------------------------------------------------------------- ws guard

__global__ __launch_bounds__(256) void k_diag(float* __restrict__ out, int n, float v) {
  int i = blockIdx.x * 256 + threadIdx.x;
  if (i < n) out[i] = v;
}

// ---------------------------------------------------------------- fused prep
// blocks [0, cum10): fp32->bf16 weight conversion (10 segments)
// blocks [cum10, cum10+128): zero pad rows of hpad
// blocks [cum10+128, cum10+134): concat qkv bias
struct PrepArgs {
  const float* s[10];
  bf16* d[10];
  int cum[11];
  bf16* hpad;
  const float* bq;
  const float* bk;
  const float* bv;
  float* qb;
};

__global__ __launch_bounds__(256) void k_prep_all(PrepArgs a) {
  int blk = blockIdx.x;
  int cum10 = a.cum[10];
  if (blk < cum10) {
    int seg = 0;
#pragma unroll
    for (int t = 0; t < 10; ++t)
      if (blk >= a.cum[t + 1]) seg = t + 1;
    const float* src = a.s[seg];
    bf16* dst = a.d[seg];
    int i = ((blk - a.cum[seg]) * 256 + threadIdx.x) * 4;
    float4 v = *reinterpret_cast<const float4*>(src + i);
    dst[i]     = (bf16)v.x;
    dst[i + 1] = (bf16)v.y;
    dst[i + 2] = (bf16)v.z;
    dst[i + 3] = (bf16)v.w;
  } else if (blk < cum10 + 128) {
    int i = (blk - cum10) * 256 + threadIdx.x;       // NB*32*128 chunks of 8
    int b = i / (32 * 128);
    int r = (i >> 7) & 31;
    int c8 = (i & 127) * 8;
    int row = (r < PADW) ? r : 1024 + r;             // 0..14, 1039..1055
    uint4v z = {0u, 0u, 0u, 0u};
    *reinterpret_cast<uint4v*>(&a.hpad[((size_t)b * HPRA + row) * CONV_INNER + c8]) = z;
  } else {
    int i = (blk - cum10 - 128) * 256 + threadIdx.x;
    if (i < 512) a.qb[i] = a.bq[i];
    else if (i < 1024) a.qb[i] = a.bk[i - 512];
    else if (i < 1536) a.qb[i] = a.bv[i - 1024];
  }
}

// dconv_w [O=1024][I=1024][K=31] fp32 -> wt [k][o][i] bf16 (vectorized 16B stores)
__global__ __launch_bounds__(256) void k_conv_wt(const float* __restrict__ w,
                                                 bf16* __restrict__ wt) {
  __shared__ float t[256 * KW];   // [i_local][k]
  int o = blockIdx.x, i0 = blockIdx.y * 256;
  const float* src = w + (size_t)o * (CONV_INNER * KW) + (size_t)i0 * KW;
  for (int idx = threadIdx.x; idx < 256 * KW; idx += 256) t[idx] = src[idx];
  __syncthreads();
  for (int idx = threadIdx.x; idx < KW * 32; idx += 256) {
    int k = idx >> 5, c = idx & 31;
    bf16x8 v;
#pragma unroll
    for (int e = 0; e < 8; ++e) v[e] = (bf16)t[(c * 8 + e) * KW + k];
    *reinterpret_cast<bf16x8*>(
        &wt[((size_t)k * CONV_INNER + o) * CONV_INNER + i0 + c * 8]) = v;
  }
}

__global__ __launch_bounds__(256) void k_transpose_in(const float* __restrict__ x,
                                                      const float* __restrict__ g,
                                                      const float* __restrict__ bvec,
                                                      float* __restrict__ xT,
                                                      bf16* __restrict__ xbn) {
  __shared__ float t[32][33];
  int s0 = blockIdx.x * 32, c0 = blockIdx.y * 32, b = blockIdx.z;
  int col = threadIdx.x & 31, rq = threadIdx.x >> 5;
#pragma unroll
  for (int i = 0; i < 4; ++i) {
    int row = rq + i * 8;
    t[row][col] = x[((size_t)b * DIM + c0 + row) * SEQ + s0 + col];
  }
  __syncthreads();
  float gg = g[c0 + col], bb = bvec[c0 + col];
#pragma unroll
  for (int i = 0; i < 4; ++i) {
    int srow = rq + i * 8;
    float v = t[col][srow];
    size_t off = ((size_t)b * SEQ + s0 + srow) * DIM + c0 + col;
    xT[off] = v;
    xbn[off] = (bf16)(v * gg + bb);
  }
}

// ---------------------------------------------------------------- generic GEMM v2
// Epilogues: 0 silu->bf16 | 1 res+0.5a, BN | 2 bf16 | 3 res+a, BN | 5 final BN
// transposed | 6 qkv: Q,K -> outb; V -> vtout transposed [bh][d][s]
template <int EPI>
__global__ __launch_bounds__(256) void k_gemm(const bf16* __restrict__ A,
                                              const bf16* __restrict__ W,
                                              const float* __restrict__ bias,
                                              const float* __restrict__ res,
                                              const float* __restrict__ g,
                                              const float* __restrict__ bb,
                                              float* __restrict__ outf,
                                              bf16* __restrict__ outb,
                                              bf16* __restrict__ vtout, int N, int K) {
  __shared__ __align__(16) bf16 sA[2][128 * 64];
  __shared__ __align__(16) bf16 sB[2][128 * 64];
  const int tid = threadIdx.x;
  const int b = blockIdx.z;
  const int m0 = blockIdx.y * 128, n0 = blockIdx.x * 128;
  const int lane = tid & 63, wid = tid >> 6;
  const int wm = (wid & 1) * 64, wn = (wid >> 1) * 64;
  const int fr = lane & 15, fg = lane >> 4;
  const int srow = lane >> 3;
  const int scol = ((lane & 7) ^ srow) * 8;

  f32x4 acc[4][4];
#pragma unroll
  for (int i = 0; i < 4; ++i)
#pragma unroll
    for (int j = 0; j < 4; ++j) acc[i][j] = (f32x4)0.f;

  const bf16* Abase = A + ((size_t)b * SEQ + m0 + srow) * K + scol;
  const bf16* Wbase = W + (size_t)(n0 + srow) * K + scol;
  const int nch = K >> 6;

#pragma unroll
  for (int c = 0; c < 4; ++c) {
    const int ch = wid + c * 4;
    gld16(Abase + (size_t)(ch * 8) * K, &sA[0][ch * 512]);
    gld16(Wbase + (size_t)(ch * 8) * K, &sB[0][ch * 512]);
  }
  __syncthreads();

  int buf = 0;
  for (int kt = 0; kt < nch; ++kt) {
    if (kt + 1 < nch) {
      const int kc = (kt + 1) * 64;
#pragma unroll
      for (int c = 0; c < 4; ++c) {
        const int ch = wid + c * 4;
        gld16(Abase + (size_t)(ch * 8) * K + kc, &sA[buf ^ 1][ch * 512]);
        gld16(Wbase + (size_t)(ch * 8) * K + kc, &sB[buf ^ 1][ch * 512]);
      }
    }
#pragma unroll
    for (int kk = 0; kk < 2; ++kk) {
      const int cg = kk * 4 + fg;
      bf16x8 aF[4], bF[4];
#pragma unroll
      for (int i = 0; i < 4; ++i) {
        const int ar = wm + i * 16 + fr;
        aF[i] = *reinterpret_cast<const bf16x8*>(
            &sA[buf][ar * 64 + ((cg ^ (ar & 7)) * 8)]);
        const int br = wn + i * 16 + fr;
        bF[i] = *reinterpret_cast<const bf16x8*>(
            &sB[buf][br * 64 + ((cg ^ (br & 7)) * 8)]);
      }
#pragma unroll
      for (int mi = 0; mi < 4; ++mi)
#pragma unroll
        for (int ni = 0; ni < 4; ++ni)
          acc[mi][ni] = __builtin_amdgcn_mfma_f32_16x16x32_bf16(aF[mi], bF[ni],
                                                                acc[mi][ni], 0, 0, 0);
    }
    __syncthreads();
    buf ^= 1;
  }

#pragma unroll
  for (int mi = 0; mi < 4; ++mi) {
#pragma unroll
    for (int ni = 0; ni < 4; ++ni) {
      int ncol = n0 + wn + ni * 16 + fr;
      float bv = bias[ncol];
      if constexpr (EPI == 5) {
        float gg = g[ncol], bbv = bb[ncol];
        int mrow0 = m0 + wm + mi * 16 + fg * 4;
        float v[4];
#pragma unroll
        for (int j = 0; j < 4; ++j) {
          float a = acc[mi][ni][j] + bv;
          float r = res[((size_t)b * SEQ + mrow0 + j) * 512 + ncol] + 0.5f * a;
          v[j] = r * gg + bbv;
        }
        *reinterpret_cast<float4*>(outf + ((size_t)b * 512 + ncol) * SEQ + mrow0) =
            make_float4(v[0], v[1], v[2], v[3]);
      } else {
#pragma unroll
        for (int j = 0; j < 4; ++j) {
          int mrow = m0 + wm + mi * 16 + fg * 4 + j;
          size_t off = ((size_t)b * SEQ + mrow) * N + ncol;
          float a = acc[mi][ni][j] + bv;
          if constexpr (EPI == 0) {
            outb[off] = (bf16)fsilu(a);
          } else if constexpr (EPI == 2) {
            outb[off] = (bf16)a;
          } else if constexpr (EPI == 6) {
            if (ncol < 1024) {
              outb[off] = (bf16)a;
            } else {
              int d = ncol - 1024;
              vtout[(((size_t)b * 8 + (d >> 6)) * 64 + (d & 63)) * SEQ + mrow] =
                  (bf16)a;
            }
          } else if constexpr (EPI == 1) {
            float r = res[off] + 0.5f * a;
            outf[off] = r;
            outb[off] = (bf16)(r * g[ncol] + bb[ncol]);
          } else if constexpr (EPI == 3) {
            float r = res[off] + a;
            outf[off] = r;
            outb[off] = (bf16)(r * g[ncol] + bb[ncol]);
          }
        }
      }
    }
  }
}

// ---------------------------------------------------------------- pw1 + GLU fused v2
__global__ __launch_bounds__(256) void k_pw1_glu(const bf16* __restrict__ A,
                                                 const bf16* __restrict__ W,
                                                 const float* __restrict__ bias,
                                                 bf16* __restrict__ hpad) {
  __shared__ __align__(16) bf16 sA[128 * 64];
  __shared__ __align__(16) bf16 sBa[128 * 64];
  __shared__ __align__(16) bf16 sBg[128 * 64];
  const int tid = threadIdx.x;
  const int b = blockIdx.z;
  const int m0 = blockIdx.y * 128, n0 = blockIdx.x * 128;
  const int lane = tid & 63, wid = tid >> 6;
  const int wm = (wid & 1) * 64, wn = (wid >> 1) * 64;
  const int fr = lane & 15, fg = lane >> 4;
  const int srow = lane >> 3;
  const int scol = ((lane & 7) ^ srow) * 8;
  const int K = 512;

  f32x4 accA[4][4], accG[4][4];
#pragma unroll
  for (int i = 0; i < 4; ++i)
#pragma unroll
    for (int j = 0; j < 4; ++j) { accA[i][j] = (f32x4)0.f; accG[i][j] = (f32x4)0.f; }

  const bf16* Abase = A + ((size_t)b * SEQ + m0 + srow) * K + scol;
  const bf16* WaB = W + (size_t)(n0 + srow) * K + scol;
  const bf16* WgB = W + (size_t)(n0 + 1024 + srow) * K + scol;

  for (int kt = 0; kt < 8; ++kt) {
    const int kc = kt * 64;
#pragma unroll
    for (int c = 0; c < 4; ++c) {
      const int ch = wid + c * 4;
      gld16(Abase + (size_t)(ch * 8) * K + kc, &sA[ch * 512]);
      gld16(WaB + (size_t)(ch * 8) * K + kc, &sBa[ch * 512]);
      gld16(WgB + (size_t)(ch * 8) * K + kc, &sBg[ch * 512]);
    }
    __syncthreads();
#pragma unroll
    for (int kk = 0; kk < 2; ++kk) {
      const int cg = kk * 4 + fg;
      bf16x8 aF[4], bFa[4], bFg[4];
#pragma unroll
      for (int i = 0; i < 4; ++i) {
        const int ar = wm + i * 16 + fr;
        aF[i] = *reinterpret_cast<const bf16x8*>(
            &sA[ar * 64 + ((cg ^ (ar & 7)) * 8)]);
        const int br = wn + i * 16 + fr;
        bFa[i] = *reinterpret_cast<const bf16x8*>(
            &sBa[br * 64 + ((cg ^ (br & 7)) * 8)]);
        bFg[i] = *reinterpret_cast<const bf16x8*>(
            &sBg[br * 64 + ((cg ^ (br & 7)) * 8)]);
      }
#pragma unroll
      for (int mi = 0; mi < 4; ++mi)
#pragma unroll
        for (int ni = 0; ni < 4; ++ni) {
          accA[mi][ni] =
              __builtin_amdgcn_mfma_f32_16x16x32_bf16(aF[mi], bFa[ni], accA[mi][ni], 0, 0, 0);
          accG[mi][ni] =
              __builtin_amdgcn_mfma_f32_16x16x32_bf16(aF[mi], bFg[ni], accG[mi][ni], 0, 0, 0);
        }
    }
    __syncthreads();
  }

#pragma unroll
  for (int mi = 0; mi < 4; ++mi) {
#pragma unroll
    for (int ni = 0; ni < 4; ++ni) {
      int ncol = n0 + wn + ni * 16 + fr;
      float ba = bias[ncol], bg = bias[ncol + 1024];
#pragma unroll
      for (int j = 0; j < 4; ++j) {
        int mrow = m0 + wm + mi * 16 + fg * 4 + j;
        float av = accA[mi][ni][j] + ba;
        float gv = accG[mi][ni][j] + bg;
        hpad[((size_t)b * HPRA + PADW + mrow) * CONV_INNER + ncol] =
            (bf16)(av * fsigmoid(gv));
      }
    }
  }
}

// ---------------------------------------------------------------- conv GEMM v8
// 128x128 block, 64x64 wave tile, K-chunk 64, XOR swizzle, A AND B double
// buffered with continuous cross-chunk pipeline. LDS 72 KB, 2 blocks/CU.
__global__ __launch_bounds__(256) void k_conv(const bf16* __restrict__ hpad,
                                              const bf16* __restrict__ wt,
                                              const float* __restrict__ bias,
                                              const float* __restrict__ g,
                                              const float* __restrict__ bb,
                                              bf16* __restrict__ outb) {
  __shared__ __align__(16) bf16 sA0[160 * 64];     // 20 KB
  __shared__ __align__(16) bf16 sA1[160 * 64];     // 20 KB
  __shared__ __align__(16) bf16 sB0[128 * 64];     // 16 KB
  __shared__ __align__(16) bf16 sB1[128 * 64];     // 16 KB
  const int tid = threadIdx.x;
  const int b = blockIdx.z;
  const int n0 = blockIdx.x * 128, m0 = blockIdx.y * 128;
  const int lane = tid & 63, wid = tid >> 6;
  const int wm = (wid & 1) * 64, wn = (wid >> 1) * 64;
  const int fr = lane & 15, fg = lane >> 4;
  const int srow = lane >> 3;
  const int scol = ((lane & 7) ^ srow) * 8;
  const size_t WKS = (size_t)CONV_INNER * CONV_INNER;

  f32x4 acc[4][4];
#pragma unroll
  for (int i = 0; i < 4; ++i)
#pragma unroll
    for (int j = 0; j < 4; ++j) acc[i][j] = (f32x4)0.f;

  const bf16* Abase = hpad + ((size_t)b * HPRA + m0 + srow) * CONV_INNER + scol;
  const bf16* Wbase = wt + (size_t)(n0 + srow) * CONV_INNER + scol;

  bf16* aCur = sA0; bf16* aNxt = sA1;
  bf16* bCur = sB0; bf16* bNxt = sB1;

  // prologue: A(0), B(0,0)
#pragma unroll
  for (int c = 0; c < 5; ++c) {
    const int ch = wid + c * 4;
    gld16(Abase + (size_t)(ch * 8) * CONV_INNER, &aCur[ch * 512]);
  }
#pragma unroll
  for (int c = 0; c < 4; ++c) {
    const int ch = wid + c * 4;
    gld16(Wbase + (size_t)(ch * 8) * CONV_INNER, &bCur[ch * 512]);
  }
  __syncthreads();

  for (int it = 0; it < 16; ++it) {
    const int itc = it * 64;
    for (int ks = 0; ks < KW; ++ks) {
      // B prefetch: next tap, or first tap of next chunk
      if (ks + 1 < KW) {
#pragma unroll
        for (int c = 0; c < 4; ++c) {
          const int ch = wid + c * 4;
          gld16(Wbase + (size_t)(ks + 1) * WKS + (size_t)(ch * 8) * CONV_INNER + itc,
                &bNxt[ch * 512]);
        }
      } else if (it + 1 < 16) {
#pragma unroll
        for (int c = 0; c < 4; ++c) {
          const int ch = wid + c * 4;
          gld16(Wbase + (size_t)(ch * 8) * CONV_INNER + itc + 64, &bNxt[ch * 512]);
        }
      }
      // A prefetch for next chunk while aNxt is idle
      if (ks == KW - 2 && it + 1 < 16) {
#pragma unroll
        for (int c = 0; c < 5; ++c) {
          const int ch = wid + c * 4;
          gld16(Abase + (size_t)(ch * 8) * CONV_INNER + itc + 64, &aNxt[ch * 512]);
        }
      }
#pragma unroll
      for (int kk = 0; kk < 2; ++kk) {
        const int cg = kk * 4 + fg;
        bf16x8 aF[4], bF[4];
#pragma unroll
        for (int i = 0; i < 4; ++i) {
          const int ar = ks + wm + i * 16 + fr;
          aF[i] = *reinterpret_cast<const bf16x8*>(
              &aCur[ar * 64 + ((cg ^ (ar & 7)) * 8)]);
        }
#pragma unroll
        for (int n = 0; n < 4; ++n) {
          const int br = wn + n * 16 + fr;
          bF[n] = *reinterpret_cast<const bf16x8*>(
              &bCur[br * 64 + ((cg ^ (br & 7)) * 8)]);
        }
#pragma unroll
        for (int mi = 0; mi < 4; ++mi)
#pragma unroll
          for (int ni = 0; ni < 4; ++ni)
            acc[mi][ni] = __builtin_amdgcn_mfma_f32_16x16x32_bf16(aF[mi], bF[ni],
                                                                  acc[mi][ni], 0, 0, 0);
      }
      __syncthreads();
      bf16* t = bCur; bCur = bNxt; bNxt = t;
    }
    bf16* t = aCur; aCur = aNxt; aNxt = t;
  }

#pragma unroll
  for (int mi = 0; mi < 4; ++mi) {
#pragma unroll
    for (int ni = 0; ni < 4; ++ni) {
      int ncol = n0 + wn + ni * 16 + fr;
      float bv = bias[ncol], gg = g[ncol], bbv = bb[ncol];
#pragma unroll
      for (int j = 0; j < 4; ++j) {
        int mrow = m0 + wm + mi * 16 + fg * 4 + j;
        float a = acc[mi][ni][j] + bv;
        outb[((size_t)b * SEQ + mrow) * CONV_INNER + ncol] = (bf16)fsilu(a * gg + bbv);
      }
    }
  }
}

// ---------------------------------------------------------------- flash attention
__global__ __launch_bounds__(256) void k_attn(const bf16* __restrict__ qkv,
                                              const bf16* __restrict__ vT,
                                              bf16* __restrict__ out) {
  __shared__ __align__(16) bf16 sQ[128][72];
  __shared__ __align__(16) bf16 sK[64][72];
  __shared__ __align__(16) bf16 sVT[64][72];
  __shared__ __align__(16) bf16 sP[128][72];
  const int tid = threadIdx.x;
  const int bh = blockIdx.y;
  const int b = bh >> 3, h = bh & 7;
  const int m0 = blockIdx.x * 128;
  const int lane = tid & 63, wid = tid >> 6;
  const int w32 = wid * 32;
  const int fr = lane & 15, fg = lane >> 4;
  const size_t base = (size_t)b * SEQ * 1536;
  const size_t vbase = (size_t)bh * 64 * SEQ;

  for (int idx = tid; idx < 128 * 8; idx += 256) {
    int row = idx >> 3, c = (idx & 7) * 8;
    *reinterpret_cast<uint4v*>(&sQ[row][c]) =
        *reinterpret_cast<const uint4v*>(qkv + base + (size_t)(m0 + row) * 1536 + h * 64 + c);
  }

  f32x4 o[2][4];
  float mst[2][4], lst[2][4];
#pragma unroll
  for (int mi = 0; mi < 2; ++mi)
#pragma unroll
    for (int j = 0; j < 4; ++j) {
      mst[mi][j] = -1e30f;
      lst[mi][j] = 0.f;
#pragma unroll
      for (int df = 0; df < 4; ++df) o[mi][df] = (f32x4)0.f;
    }

  for (int t0 = 0; t0 < SEQ; t0 += 64) {
    for (int idx = tid; idx < 64 * 8; idx += 256) {
      int row = idx >> 3, c = (idx & 7) * 8;
      *reinterpret_cast<uint4v*>(&sK[row][c]) = *reinterpret_cast<const uint4v*>(
          qkv + base + (size_t)(t0 + row) * 1536 + 512 + h * 64 + c);
      *reinterpret_cast<uint4v*>(&sVT[row][c]) = *reinterpret_cast<const uint4v*>(
          vT + vbase + (size_t)row * SEQ + t0 + c);
    }
    __syncthreads();

    f32x4 sacc[2][4];
#pragma unroll
    for (int mi = 0; mi < 2; ++mi)
#pragma unroll
      for (int tf = 0; tf < 4; ++tf) sacc[mi][tf] = (f32x4)0.f;
#pragma unroll
    for (int kk = 0; kk < 2; ++kk) {
      bf16x8 aQ[2], bK[4];
#pragma unroll
      for (int mi = 0; mi < 2; ++mi)
        aQ[mi] = *reinterpret_cast<const bf16x8*>(&sQ[w32 + mi * 16 + fr][kk * 32 + fg * 8]);
#pragma unroll
      for (int tf = 0; tf < 4; ++tf)
        bK[tf] = *reinterpret_cast<const bf16x8*>(&sK[tf * 16 + fr][kk * 32 + fg * 8]);
#pragma unroll
      for (int mi = 0; mi < 2; ++mi)
#pragma unroll
        for (int tf = 0; tf < 4; ++tf)
          sacc[mi][tf] =
              __builtin_amdgcn_mfma_f32_16x16x32_bf16(aQ[mi], bK[tf], sacc[mi][tf], 0, 0, 0);
    }

#pragma unroll
    for (int mi = 0; mi < 2; ++mi) {
#pragma unroll
      for (int j = 0; j < 4; ++j) {
        float rm = -1e30f;
#pragma unroll
        for (int tf = 0; tf < 4; ++tf) rm = fmaxf(rm, sacc[mi][tf][j] * 0.125f);
#pragma unroll
        for (int off = 1; off < 16; off <<= 1) rm = fmaxf(rm, __shfl_xor(rm, off));
        float mnew = fmaxf(mst[mi][j], rm);
        float al = __expf(mst[mi][j] - mnew);
        float ps = 0.f;
#pragma unroll
        for (int tf = 0; tf < 4; ++tf) {
          float p = __expf(sacc[mi][tf][j] * 0.125f - mnew);
          ps += p;
          sP[w32 + mi * 16 + fg * 4 + j][tf * 16 + fr] = (bf16)p;
        }
#pragma unroll
        for (int off = 1; off < 16; off <<= 1) ps += __shfl_xor(ps, off);
        lst[mi][j] = lst[mi][j] * al + ps;
        mst[mi][j] = mnew;
#pragma unroll
        for (int df = 0; df < 4; ++df) o[mi][df][j] *= al;
      }
    }
    __syncthreads();

#pragma unroll
    for (int kk = 0; kk < 2; ++kk) {
      bf16x8 aP[2], bV[4];
#pragma unroll
      for (int mi = 0; mi < 2; ++mi)
        aP[mi] = *reinterpret_cast<const bf16x8*>(&sP[w32 + mi * 16 + fr][kk * 32 + fg * 8]);
#pragma unroll
      for (int df = 0; df < 4; ++df)
        bV[df] = *reinterpret_cast<const bf16x8*>(&sVT[df * 16 + fr][kk * 32 + fg * 8]);
#pragma unroll
      for (int mi = 0; mi < 2; ++mi)
#pragma unroll
        for (int df = 0; df < 4; ++df)
          o[mi][df] = __builtin_amdgcn_mfma_f32_16x16x32_bf16(aP[mi], bV[df], o[mi][df], 0, 0, 0);
    }
    __syncthreads();
  }

#pragma unroll
  for (int mi = 0; mi < 2; ++mi)
#pragma unroll
    for (int df = 0; df < 4; ++df)
#pragma unroll
      for (int j = 0; j < 4; ++j) {
        int row = m0 + w32 + mi * 16 + fg * 4 + j;
        int col = h * 64 + df * 16 + fr;
        out[((size_t)b * SEQ + row) * 512 + col] = (bf16)(o[mi][df][j] / lst[mi][j]);
      }
}

// ---------------------------------------------------------------- launcher

extern "C" void kernel_launch(void* const* d_in, const int* in_sizes, int n_in,
                              void* d_out, int out_size, void* d_ws, size_t ws_size,
                              hipStream_t stream) {
  const float* x      = (const float*)d_in[0];
  const float* ff1_g  = (const float*)d_in[1];
  const float* ff1_b  = (const float*)d_in[2];
  const float* ff1_w1 = (const float*)d_in[3];
  const float* ff1_b1 = (const float*)d_in[4];
  const float* ff1_w2 = (const float*)d_in[5];
  const float* ff1_b2 = (const float*)d_in[6];
  const float* attn_g = (const float*)d_in[7];
  const float* attn_b = (const float*)d_in[8];
  const float* wq     = (const float*)d_in[9];
  const float* bq     = (const float*)d_in[10];
  const float* wk     = (const float*)d_in[11];
  const float* bk     = (const float*)d_in[12];
  const float* wv     = (const float*)d_in[13];
  const float* bv     = (const float*)d_in[14];
  const float* wo     = (const float*)d_in[15];
  const float* bo     = (const float*)d_in[16];
  const float* conv_g = (const float*)d_in[17];
  const float* conv_b = (const float*)d_in[18];
  const float* pw1_w  = (const float*)d_in[19];
  const float* pw1_b  = (const float*)d_in[20];
  const float* dconv_w = (const float*)d_in[21];
  const float* dconv_b = (const float*)d_in[22];
  const float* cbn_g  = (const float*)d_in[23];
  const float* cbn_b  = (const float*)d_in[24];
  const float* pw2_w  = (const float*)d_in[25];
  const float* pw2_b  = (const float*)d_in[26];
  const float* ff2_g  = (const float*)d_in[27];
  const float* ff2_b  = (const float*)d_in[28];
  const float* ff2_w1 = (const float*)d_in[29];
  const float* ff2_b1 = (const float*)d_in[30];
  const float* ff2_w2 = (const float*)d_in[31];
  const float* ff2_b2 = (const float*)d_in[32];
  const float* fin_g  = (const float*)d_in[33];
  const float* fin_b  = (const float*)d_in[34];

  char* ws = (char*)d_ws;
  size_t off = 0;
  auto alloc = [&](size_t bytes) -> void* {
    off = (off + 255) & ~(size_t)255;
    void* p = ws + off;
    off += bytes;
    return p;
  };

  // ---- persistent small weights (~9.4 MB)
  bf16* wqkv  = (bf16*)alloc((size_t)1536 * 512 * 2);
  float* qkvb = (float*)alloc(1536 * 4);
  bf16* wf1a  = (bf16*)alloc((size_t)1024 * 512 * 2);
  bf16* wf1b  = (bf16*)alloc((size_t)512 * 1024 * 2);
  bf16* wwo   = (bf16*)alloc((size_t)512 * 512 * 2);
  bf16* wpw1  = (bf16*)alloc((size_t)2048 * 512 * 2);
  bf16* wpw2  = (bf16*)alloc((size_t)512 * 1024 * 2);
  bf16* wf2a  = (bf16*)alloc((size_t)1024 * 512 * 2);
  bf16* wf2b  = (bf16*)alloc((size_t)512 * 1024 * 2);

  // ---- persistent activation buffers
  bf16*  Bn  = (bf16*)alloc((size_t)NB * SEQ * 512 * 2);    // 8MB
  float* F1  = (float*)alloc((size_t)NB * SEQ * 512 * 4);   // 16MB
  bf16*  HGp = (bf16*)alloc((size_t)NB * HPRA * 1024 * 2);  // 17.3MB
  bf16*  H2  = (bf16*)alloc((size_t)NB * SEQ * 1024 * 2);   // 16MB

  // ---- big region E (62MB)
  char* E = (char*)alloc((size_t)KW * 1024 * 1024 * 2);
  bf16*  wt     = (bf16*)E;
  bf16*  h1     = (bf16*)E;
  bf16*  qkv    = (bf16*)E;
  bf16*  attn_o = (bf16*)(E + (size_t)24 * 1024 * 1024);
  float* x1     = (float*)(E + (size_t)32 * 1024 * 1024);
  bf16*  vT     = (bf16*)(E + (size_t)48 * 1024 * 1024);
  float* x3     = (float*)E;
  bf16*  h3     = (bf16*)(E + (size_t)16 * 1024 * 1024);

  float* xT = F1;
  float* x2 = F1;
  bf16* xbn = Bn, *x1bn = Bn, *x2bn = Bn, *x3bn = Bn;
  size_t needed = off;
  (void)in_sizes; (void)n_in;

  if (ws_size < needed) {
    k_diag<<<(out_size + 255) / 256, 256, 0, stream>>>(
        (float*)d_out, out_size, (float)(ws_size >> 20));
    return;
  }

  // ---- fused prep: weight conversion + pad-zero + bias concat (one launch)
  PrepArgs pa;
  pa.s[0] = wq;      pa.d[0] = wqkv;
  pa.s[1] = wk;      pa.d[1] = wqkv + 512 * 512;
  pa.s[2] = wv;      pa.d[2] = wqkv + 1024 * 512;
  pa.s[3] = ff1_w1;  pa.d[3] = wf1a;
  pa.s[4] = ff1_w2;  pa.d[4] = wf1b;
  pa.s[5] = wo;      pa.d[5] = wwo;
  pa.s[6] = pw1_w;   pa.d[6] = wpw1;
  pa.s[7] = pw2_w;   pa.d[7] = wpw2;
  pa.s[8] = ff2_w1;  pa.d[8] = wf2a;
  pa.s[9] = ff2_w2;  pa.d[9] = wf2b;
  int blocks1024[10] = {256, 256, 256, 512, 512, 256, 1024, 512, 512, 512};
  int cum = 0;
  for (int i = 0; i < 10; ++i) { pa.cum[i] = cum; cum += blocks1024[i]; }
  pa.cum[10] = cum;
  pa.hpad = HGp;
  pa.bq = bq; pa.bk = bk; pa.bv = bv; pa.qb = qkvb;
  k_prep_all<<<cum + 128 + 6, 256, 0, stream>>>(pa);
  k_transpose_in<<<dim3(32, 16, NB), 256, 0, stream>>>(x, ff1_g, ff1_b, xT, xbn);

  // ---- FF1
  k_gemm<0><<<dim3(8, 8, NB), 256, 0, stream>>>(xbn, wf1a, ff1_b1, nullptr, nullptr,
                                                nullptr, nullptr, h1, nullptr, 1024, 512);
  k_gemm<1><<<dim3(4, 8, NB), 256, 0, stream>>>(h1, wf1b, ff1_b2, xT, attn_g, attn_b,
                                                x1, x1bn, nullptr, 512, 1024);
  // ---- attention
  k_gemm<6><<<dim3(12, 8, NB), 256, 0, stream>>>(x1bn, wqkv, qkvb, nullptr, nullptr,
                                                 nullptr, nullptr, qkv, vT, 1536, 512);
  k_attn<<<dim3(8, 64), 256, 0, stream>>>(qkv, vT, attn_o);
  k_gemm<3><<<dim3(4, 8, NB), 256, 0, stream>>>(attn_o, wwo, bo, x1, conv_g, conv_b,
                                                x2, x2bn, nullptr, 512, 512);
  // ---- conv weight transform (E free now)
  k_conv_wt<<<dim3(1024, 4), 256, 0, stream>>>(dconv_w, wt);
  // ---- conv module
  k_pw1_glu<<<dim3(8, 8, NB), 256, 0, stream>>>(x2bn, wpw1, pw1_b, HGp);
  k_conv<<<dim3(8, 8, NB), 256, 0, stream>>>(HGp, wt, dconv_b, cbn_g, cbn_b, H2);
  // (wt dead now -> x3/h3 reuse E)
  k_gemm<3><<<dim3(4, 8, NB), 256, 0, stream>>>(H2, wpw2, pw2_b, x2, ff2_g, ff2_b,
                                                x3, x3bn, nullptr, 512, 1024);
  // ---- FF2 + final BN (transposed store to d_out)
  k_gemm<0><<<dim3(8, 8, NB), 256, 0, stream>>>(x3bn, wf2a, ff2_b1, nullptr, nullptr,
                                                nullptr, nullptr, h3, nullptr, 1024, 512);
  k_gemm<5><<<dim3(4, 8, NB), 256, 0, stream>>>(h3, wf2b, ff2_b2, x3, fin_g, fin_b,
                                                (float*)d_out, nullptr, nullptr, 512, 1024);
}